// Round 2
// baseline (9643.504 us; speedup 1.0000x reference)
//
#include <hip/hip_runtime.h>
#include <math.h>

// Problem dims (fixed)
#define NN 16384
#define BB 32
#define HH 15
#define KK 25
#define GG 64
#define CC 6
#define EE (NN * 32)

// ---------------- CSR build ----------------

__global__ void init_counts(int* __restrict__ cnt, float* __restrict__ logits) {
    int t = blockIdx.x * 256 + threadIdx.x;
    if (t < NN) cnt[t] = 0;
    if (t < BB * CC) logits[t] = 0.f;
}

__global__ void hist_kernel(const int* __restrict__ src, int* __restrict__ cnt) {
    int e = blockIdx.x * 256 + threadIdx.x;
    if (e < EE) atomicAdd(&cnt[src[e]], 1);
}

__global__ __launch_bounds__(1024) void scan_kernel(const int* __restrict__ cnt,
                                                    int* __restrict__ rowptr,
                                                    int* __restrict__ cursor) {
    __shared__ int sums[1024];
    int t = threadIdx.x;
    int base = t * 16;
    int local[16];
    int s = 0;
#pragma unroll
    for (int i = 0; i < 16; ++i) { local[i] = s; s += cnt[base + i]; }
    sums[t] = s;
    __syncthreads();
    for (int off = 1; off < 1024; off <<= 1) {
        int v = (t >= off) ? sums[t - off] : 0;
        __syncthreads();
        sums[t] += v;
        __syncthreads();
    }
    int prefix = (t == 0) ? 0 : sums[t - 1];
#pragma unroll
    for (int i = 0; i < 16; ++i) {
        int rp = prefix + local[i];
        rowptr[base + i] = rp;
        cursor[base + i] = rp;
    }
    if (t == 1023) rowptr[NN] = sums[1023];
}

__global__ void scatter_kernel(const int* __restrict__ src, const int* __restrict__ dst,
                               const float* __restrict__ w, int* __restrict__ cursor,
                               int* __restrict__ col, float* __restrict__ wgt) {
    int e = blockIdx.x * 256 + threadIdx.x;
    if (e < EE) {
        int pos = atomicAdd(&cursor[src[e]], 1);
        col[pos] = dst[e];
        wgt[pos] = w[e];
    }
}

// ---------------- transpose chunk: X0[n][bb][16] for bb in [0,BCH) ----------------

template<int BCH>
__global__ void transpose_t(const float* __restrict__ x, float* __restrict__ X0, int b0) {
    const int C = BCH * 16;
    int t = blockIdx.x * 256 + threadIdx.x;   // t in [0, NN*C)
    int n = t / C;
    int c = t % C;
    int bb = c >> 4;
    int h = c & 15;
    float v = 0.f;
    if (h < HH) v = x[((size_t)(b0 + bb) * NN + n) * HH + h];
    X0[t] = v;
}

// ---------------- SPMM: Xout = alpha * (L @ Xin) + beta * Xprev ----------------
// C columns per node row; NPB nodes (sub-groups) per block.
// In-place on Xprev/Xout is safe: row n is read/written only by its own sub-group.

template<int C, int NPB>
__global__ __launch_bounds__(C * NPB) void spmm_t(
    const int* __restrict__ rowptr, const int* __restrict__ col, const float* __restrict__ wgt,
    const float* __restrict__ Xin, const float* __restrict__ Xprev, float* __restrict__ Xout,
    float alpha, float beta)
{
    int n, c;
    float acc = 0.f;
    if constexpr (NPB == 1) {
        n = blockIdx.x;
        c = threadIdx.x;
        __shared__ int   s_col[64];
        __shared__ float s_w[64];
        int e0 = rowptr[n], e1 = rowptr[n + 1];
        for (int base = e0; base < e1; base += 64) {
            int cnt = e1 - base;
            if (cnt > 64) cnt = 64;
            if (threadIdx.x < cnt) {
                s_col[threadIdx.x] = col[base + threadIdx.x];
                s_w[threadIdx.x]   = wgt[base + threadIdx.x];
            }
            __syncthreads();
            for (int j = 0; j < cnt; ++j)
                acc = fmaf(s_w[j], Xin[(size_t)s_col[j] * C + c], acc);
            __syncthreads();
        }
    } else {
        int sub = threadIdx.x / C;
        c = threadIdx.x % C;
        n = blockIdx.x * NPB + sub;
        int e0 = rowptr[n], e1 = rowptr[n + 1];
        for (int j = e0; j < e1; ++j) {
            int cc = col[j];
            float w = wgt[j];
            acc = fmaf(w, Xin[(size_t)cc * C + c], acc);
        }
    }
    size_t o = (size_t)n * C + c;
    float r = alpha * acc;
    if (beta != 0.f) r = fmaf(beta, Xprev[o], r);
    Xout[o] = r;
}

// ---------------- fused final per chunk: contraction + bias + relu + FC partials ----------------

template<int BCH>
__global__ __launch_bounds__(256) void final_t(
    const float* __restrict__ Xall, const float* __restrict__ W,
    const float* __restrict__ b_conv, const float* __restrict__ Wfc,
    float* __restrict__ logits, int b0)
{
    const int C = BCH * 16;
    int t = blockIdx.x * 256 + threadIdx.x;
    int n  = t / BCH;
    int bb = t % BCH;

    float acc[GG];
#pragma unroll
    for (int g = 0; g < GG; ++g) acc[g] = 0.f;

    for (int k = 0; k < KK; ++k) {
        const float4* xp = (const float4*)(Xall + ((size_t)k * NN + n) * C + bb * 16);
        float4 q0 = xp[0], q1 = xp[1], q2 = xp[2], q3 = xp[3];
        float xk[16] = { q0.x, q0.y, q0.z, q0.w,
                         q1.x, q1.y, q1.z, q1.w,
                         q2.x, q2.y, q2.z, q2.w,
                         q3.x, q3.y, q3.z, q3.w };
        const float* __restrict__ Wk = W + k * (HH * GG);
#pragma unroll
        for (int h = 0; h < HH; ++h) {
            float xv = xk[h];
#pragma unroll
            for (int g = 0; g < GG; ++g)
                acc[g] = fmaf(xv, Wk[h * GG + g], acc[g]);   // W uniform -> scalar loads
        }
    }

    float part[CC];
#pragma unroll
    for (int c = 0; c < CC; ++c) part[c] = 0.f;
    const size_t NG = (size_t)NN * GG;
#pragma unroll 8
    for (int g = 0; g < GG; ++g) {
        float hv = fmaxf(acc[g] + b_conv[g], 0.f);
        size_t colix = (size_t)n * GG + g;
#pragma unroll
        for (int c = 0; c < CC; ++c)
            part[c] = fmaf(hv, Wfc[(size_t)c * NG + colix], part[c]);
    }

    // butterfly-reduce across lanes sharing the same bb (different n within the wave)
#pragma unroll
    for (int off = BCH; off < 64; off <<= 1) {
#pragma unroll
        for (int c = 0; c < CC; ++c) part[c] += __shfl_xor(part[c], off);
    }

    __shared__ float red[BCH * CC];
    if (threadIdx.x < BCH * CC) red[threadIdx.x] = 0.f;
    __syncthreads();
    if ((threadIdx.x & 63) < BCH) {
#pragma unroll
        for (int c = 0; c < CC; ++c) atomicAdd(&red[bb * CC + c], part[c]);
    }
    __syncthreads();
    if (threadIdx.x < BCH * CC) atomicAdd(&logits[b0 * CC + threadIdx.x], red[threadIdx.x]);
}

// ---------------- log_softmax ----------------

__global__ void lsm_kernel(const float* __restrict__ logits, const float* __restrict__ b_fc,
                           float* __restrict__ out) {
    int b = threadIdx.x;
    if (b >= BB) return;
    float v[CC];
    float m = -1e30f;
#pragma unroll
    for (int c = 0; c < CC; ++c) {
        v[c] = logits[b * CC + c] + b_fc[c];
        m = fmaxf(m, v[c]);
    }
    float s = 0.f;
#pragma unroll
    for (int c = 0; c < CC; ++c) s += expf(v[c] - m);
    float ls = m + logf(s);
#pragma unroll
    for (int c = 0; c < CC; ++c) out[b * CC + c] = v[c] - ls;
}

__global__ void sentinel_kernel(float* __restrict__ out) {
    int t = threadIdx.x;
    if (t < BB * CC) out[t] = -12345.f;
}

// ---------------- per-tier pass driver ----------------

template<int BCH>
static void run_passes(const float* x, const float* W, const float* bconv, const float* Wfc,
                       const int* rowptr, const int* col, const float* wgt,
                       float* Xall, float* logits, hipStream_t stream)
{
    constexpr int C = BCH * 16;
    constexpr int NPB = (C >= 256) ? 1 : (256 / C);
    const size_t slice = (size_t)NN * C;

    for (int p = 0; p < BB / BCH; ++p) {
        int b0 = p * BCH;
        transpose_t<BCH><<<(NN * C) / 256, 256, 0, stream>>>(x, Xall, b0);
        // X1 = L @ X0
        spmm_t<C, NPB><<<NN / NPB, C * NPB, 0, stream>>>(
            rowptr, col, wgt, Xall, Xall, Xall + slice, 1.f, 0.f);
        // Xk = 2 L Xk-1 - Xk-2
        for (int k = 2; k < KK; ++k) {
            spmm_t<C, NPB><<<NN / NPB, C * NPB, 0, stream>>>(
                rowptr, col, wgt,
                Xall + (size_t)(k - 1) * slice,
                Xall + (size_t)(k - 2) * slice,
                Xall + (size_t)k * slice, 2.f, -1.f);
        }
        final_t<BCH><<<(NN * BCH) / 256, 256, 0, stream>>>(Xall, W, bconv, Wfc, logits, b0);
    }
}

// ---------------- launch ----------------

extern "C" void kernel_launch(void* const* d_in, const int* in_sizes, int n_in,
                              void* d_out, int out_size, void* d_ws, size_t ws_size,
                              hipStream_t stream) {
    const float* x     = (const float*)d_in[0];
    const float* ew    = (const float*)d_in[1];
    const float* W     = (const float*)d_in[2];
    const float* bconv = (const float*)d_in[3];
    const float* Wfc   = (const float*)d_in[4];
    const float* bfc   = (const float*)d_in[5];
    const int*   esrc  = (const int*)d_in[6];
    const int*   edst  = (const int*)d_in[7];
    float* out = (float*)d_out;

    char* ws = (char*)d_ws;
    size_t off = 0;
    auto alloc = [&](size_t bytes) -> void* {
        void* p = (void*)(ws + off);
        off = (off + bytes + 255) & ~(size_t)255;
        return p;
    };
    int*   rowptr = (int*)  alloc((size_t)(NN + 1) * 4);
    int*   cursor = (int*)  alloc((size_t)NN * 4);
    int*   cnt    = (int*)  alloc((size_t)NN * 4);
    int*   col    = (int*)  alloc((size_t)EE * 4);
    float* wgt    = (float*)alloc((size_t)EE * 4);
    float* logits = (float*)alloc(256 * 4);
    size_t fixed = off;

    int BCH = 0;
    for (int b = 32; b >= 1; b >>= 1) {
        size_t need = fixed + (size_t)KK * NN * (size_t)b * 16 * 4;
        if (need <= ws_size) { BCH = b; break; }
    }
    if (BCH == 0) {  // ws too small even for BCH=1 (~31 MB): make it visible
        sentinel_kernel<<<1, 256, 0, stream>>>(out);
        return;
    }
    float* Xall = (float*)(ws + fixed);

    init_counts<<<(NN + 255) / 256, 256, 0, stream>>>(cnt, logits);
    hist_kernel<<<(EE + 255) / 256, 256, 0, stream>>>(esrc, cnt);
    scan_kernel<<<1, 1024, 0, stream>>>(cnt, rowptr, cursor);
    scatter_kernel<<<(EE + 255) / 256, 256, 0, stream>>>(esrc, edst, ew, cursor, col, wgt);

    switch (BCH) {
        case 32: run_passes<32>(x, W, bconv, Wfc, rowptr, col, wgt, Xall, logits, stream); break;
        case 16: run_passes<16>(x, W, bconv, Wfc, rowptr, col, wgt, Xall, logits, stream); break;
        case 8:  run_passes<8>(x, W, bconv, Wfc, rowptr, col, wgt, Xall, logits, stream); break;
        case 4:  run_passes<4>(x, W, bconv, Wfc, rowptr, col, wgt, Xall, logits, stream); break;
        case 2:  run_passes<2 >(x, W, bconv, Wfc, rowptr, col, wgt, Xall, logits, stream); break;
        default: run_passes<1 >(x, W, bconv, Wfc, rowptr, col, wgt, Xall, logits, stream); break;
    }

    lsm_kernel<<<1, 64, 0, stream>>>(logits, bfc, out);
}

// Round 3
// 4566.434 us; speedup vs baseline: 2.1118x; 2.1118x over previous
//
#include <hip/hip_runtime.h>
#include <math.h>

// Problem dims (fixed)
#define NN 16384
#define BB 32
#define HH 15
#define KK 25
#define GG 64
#define CC 6
#define EE (NN * 32)
#define NG ((size_t)NN * GG)

// ---------------- CSR build ----------------

__global__ void init_counts(int* __restrict__ cnt, float* __restrict__ logits) {
    int t = blockIdx.x * 256 + threadIdx.x;
    if (t < NN) cnt[t] = 0;
    if (t < BB * CC) logits[t] = 0.f;
}

__global__ void hist_kernel(const int* __restrict__ src, int* __restrict__ cnt) {
    int e = blockIdx.x * 256 + threadIdx.x;
    if (e < EE) atomicAdd(&cnt[src[e]], 1);
}

__global__ __launch_bounds__(1024) void scan_kernel(const int* __restrict__ cnt,
                                                    int* __restrict__ rowptr,
                                                    int* __restrict__ cursor) {
    __shared__ int sums[1024];
    int t = threadIdx.x;
    int base = t * 16;
    int local[16];
    int s = 0;
#pragma unroll
    for (int i = 0; i < 16; ++i) { local[i] = s; s += cnt[base + i]; }
    sums[t] = s;
    __syncthreads();
    for (int off = 1; off < 1024; off <<= 1) {
        int v = (t >= off) ? sums[t - off] : 0;
        __syncthreads();
        sums[t] += v;
        __syncthreads();
    }
    int prefix = (t == 0) ? 0 : sums[t - 1];
#pragma unroll
    for (int i = 0; i < 16; ++i) {
        int rp = prefix + local[i];
        rowptr[base + i] = rp;
        cursor[base + i] = rp;
    }
    if (t == 1023) rowptr[NN] = sums[1023];
}

__global__ void scatter_kernel(const int* __restrict__ src, const int* __restrict__ dst,
                               const float* __restrict__ w, int* __restrict__ cursor,
                               int* __restrict__ col, float* __restrict__ wgt) {
    int e = blockIdx.x * 256 + threadIdx.x;
    if (e < EE) {
        int pos = atomicAdd(&cursor[src[e]], 1);
        col[pos] = dst[e];
        wgt[pos] = w[e];
    }
}

// ---------------- transpose chunk: X0[n][bb][16] for bb in [0,BCH) ----------------

template<int BCH>
__global__ void transpose_t(const float* __restrict__ x, float* __restrict__ X0, int b0) {
    const int C = BCH * 16;
    int t = blockIdx.x * 256 + threadIdx.x;   // t in [0, NN*C)
    int n = t / C;
    int c = t % C;
    int bb = c >> 4;
    int h = c & 15;
    float v = 0.f;
    if (h < HH) v = x[((size_t)(b0 + bb) * NN + n) * HH + h];
    X0[t] = v;
}

// ---------------- SPMM: Xout = alpha * (L @ Xin) + beta * Xprev ----------------
// One row per C threads. Edge metadata loaded lane-parallel into registers,
// broadcast per-edge via readlane (SALU) -> only the gather touches memory.

template<int C>
__global__ __launch_bounds__((C <= 256) ? 256 : C) void spmm_t(
    const int* __restrict__ rowptr, const int* __restrict__ col, const float* __restrict__ wgt,
    const float* __restrict__ Xin, const float* __restrict__ Xprev, float* __restrict__ Xout,
    float alpha, float beta)
{
    constexpr int TPB = (C <= 256) ? 256 : C;
    constexpr int RPB = TPB / C;
    int sub  = threadIdx.x / C;
    int c    = threadIdx.x % C;
    int lane = threadIdx.x & 63;
    int n = blockIdx.x * RPB + sub;
    int e0 = rowptr[n], e1 = rowptr[n + 1];

    float a0 = 0.f, a1 = 0.f, a2 = 0.f, a3 = 0.f;
    for (int base = e0; base < e1; base += 64) {
        int cnt = e1 - base;
        if (cnt > 64) cnt = 64;
        int cv = 0; float wv = 0.f;
        if (lane < cnt) { cv = col[base + lane]; wv = wgt[base + lane]; }
        int j = 0;
        for (; j + 4 <= cnt; j += 4) {
            int i0 = __builtin_amdgcn_readlane(cv, j);
            int i1 = __builtin_amdgcn_readlane(cv, j + 1);
            int i2 = __builtin_amdgcn_readlane(cv, j + 2);
            int i3 = __builtin_amdgcn_readlane(cv, j + 3);
            float w0 = __int_as_float(__builtin_amdgcn_readlane(__float_as_int(wv), j));
            float w1 = __int_as_float(__builtin_amdgcn_readlane(__float_as_int(wv), j + 1));
            float w2 = __int_as_float(__builtin_amdgcn_readlane(__float_as_int(wv), j + 2));
            float w3 = __int_as_float(__builtin_amdgcn_readlane(__float_as_int(wv), j + 3));
            float x0 = Xin[(size_t)i0 * C + c];
            float x1 = Xin[(size_t)i1 * C + c];
            float x2 = Xin[(size_t)i2 * C + c];
            float x3 = Xin[(size_t)i3 * C + c];
            a0 = fmaf(w0, x0, a0);
            a1 = fmaf(w1, x1, a1);
            a2 = fmaf(w2, x2, a2);
            a3 = fmaf(w3, x3, a3);
        }
        for (; j < cnt; ++j) {
            int i0 = __builtin_amdgcn_readlane(cv, j);
            float w0 = __int_as_float(__builtin_amdgcn_readlane(__float_as_int(wv), j));
            a0 = fmaf(w0, Xin[(size_t)i0 * C + c], a0);
        }
    }
    float acc = (a0 + a1) + (a2 + a3);
    size_t o = (size_t)n * C + c;
    float r = alpha * acc;
    if (beta != 0.f) r = fmaf(beta, Xprev[o], r);
    Xout[o] = r;
}

// ---------------- fused final per chunk ----------------
// 64-thread blocks, thread = (n, bb). W[k] staged in LDS (broadcast reads).

template<int BCH>
__global__ __launch_bounds__(64) void final_t(
    const float* __restrict__ Xall, const float* __restrict__ W,
    const float* __restrict__ b_conv, const float* __restrict__ Wfc,
    float* __restrict__ logits, int b0)
{
    constexpr int C = BCH * 16;
    __shared__ float sW[HH * GG];   // 3.84 KB
    int t = blockIdx.x * 64 + threadIdx.x;
    int n  = t / BCH;
    int bb = t % BCH;

    float acc[GG];
#pragma unroll
    for (int g = 0; g < GG; ++g) acc[g] = 0.f;

    for (int k = 0; k < KK; ++k) {
        __syncthreads();
        for (int i = threadIdx.x; i < HH * GG; i += 64) sW[i] = W[k * HH * GG + i];
        __syncthreads();
        const float4* xp = (const float4*)(Xall + ((size_t)k * NN + n) * C + bb * 16);
        float4 q0 = xp[0], q1 = xp[1], q2 = xp[2], q3 = xp[3];
        float xk[16] = { q0.x, q0.y, q0.z, q0.w,
                         q1.x, q1.y, q1.z, q1.w,
                         q2.x, q2.y, q2.z, q2.w,
                         q3.x, q3.y, q3.z, q3.w };
#pragma unroll
        for (int h = 0; h < HH; ++h) {
            float xv = xk[h];
#pragma unroll
            for (int g = 0; g < GG; ++g)
                acc[g] = fmaf(xv, sW[h * GG + g], acc[g]);
        }
    }

    // bias + relu + FC partials
    float part[CC];
#pragma unroll
    for (int c = 0; c < CC; ++c) part[c] = 0.f;
    const float4* bias4 = (const float4*)b_conv;
#pragma unroll
    for (int g4 = 0; g4 < GG / 4; ++g4) {
        float4 b4 = bias4[g4];
        float h0 = fmaxf(acc[4 * g4 + 0] + b4.x, 0.f);
        float h1 = fmaxf(acc[4 * g4 + 1] + b4.y, 0.f);
        float h2 = fmaxf(acc[4 * g4 + 2] + b4.z, 0.f);
        float h3 = fmaxf(acc[4 * g4 + 3] + b4.w, 0.f);
#pragma unroll
        for (int c = 0; c < CC; ++c) {
            float4 w4 = ((const float4*)(Wfc + (size_t)c * NG + (size_t)n * GG))[g4];
            part[c] = fmaf(h0, w4.x, part[c]);
            part[c] = fmaf(h1, w4.y, part[c]);
            part[c] = fmaf(h2, w4.z, part[c]);
            part[c] = fmaf(h3, w4.w, part[c]);
        }
    }

    // reduce across lanes sharing bb (stride-BCH groups)
#pragma unroll
    for (int off = BCH; off < 64; off <<= 1) {
#pragma unroll
        for (int c = 0; c < CC; ++c) part[c] += __shfl_xor(part[c], off);
    }
    if (threadIdx.x < BCH) {
#pragma unroll
        for (int c = 0; c < CC; ++c)
            atomicAdd(&logits[(b0 + threadIdx.x) * CC + c], part[c]);
    }
}

// ---------------- log_softmax ----------------

__global__ void lsm_kernel(const float* __restrict__ logits, const float* __restrict__ b_fc,
                           float* __restrict__ out) {
    int b = threadIdx.x;
    if (b >= BB) return;
    float v[CC];
    float m = -1e30f;
#pragma unroll
    for (int c = 0; c < CC; ++c) {
        v[c] = logits[b * CC + c] + b_fc[c];
        m = fmaxf(m, v[c]);
    }
    float s = 0.f;
#pragma unroll
    for (int c = 0; c < CC; ++c) s += expf(v[c] - m);
    float ls = m + logf(s);
#pragma unroll
    for (int c = 0; c < CC; ++c) out[b * CC + c] = v[c] - ls;
}

__global__ void sentinel_kernel(float* __restrict__ out) {
    int t = threadIdx.x;
    if (t < BB * CC) out[t] = -12345.f;
}

// ---------------- per-tier pass driver ----------------

template<int BCH>
static void run_passes(const float* x, const float* W, const float* bconv, const float* Wfc,
                       const int* rowptr, const int* col, const float* wgt,
                       float* Xall, float* logits, hipStream_t stream)
{
    constexpr int C = BCH * 16;
    constexpr int TPB = (C <= 256) ? 256 : C;
    constexpr int RPB = TPB / C;
    const size_t slice = (size_t)NN * C;

    for (int p = 0; p < BB / BCH; ++p) {
        int b0 = p * BCH;
        transpose_t<BCH><<<(NN * C) / 256, 256, 0, stream>>>(x, Xall, b0);
        // X1 = L @ X0
        spmm_t<C><<<NN / RPB, TPB, 0, stream>>>(
            rowptr, col, wgt, Xall, Xall, Xall + slice, 1.f, 0.f);
        // Xk = 2 L Xk-1 - Xk-2
        for (int k = 2; k < KK; ++k) {
            spmm_t<C><<<NN / RPB, TPB, 0, stream>>>(
                rowptr, col, wgt,
                Xall + (size_t)(k - 1) * slice,
                Xall + (size_t)(k - 2) * slice,
                Xall + (size_t)k * slice, 2.f, -1.f);
        }
        final_t<BCH><<<(NN * BCH) / 64, 64, 0, stream>>>(Xall, W, bconv, Wfc, logits, b0);
    }
}

// ---------------- launch ----------------

extern "C" void kernel_launch(void* const* d_in, const int* in_sizes, int n_in,
                              void* d_out, int out_size, void* d_ws, size_t ws_size,
                              hipStream_t stream) {
    const float* x     = (const float*)d_in[0];
    const float* ew    = (const float*)d_in[1];
    const float* W     = (const float*)d_in[2];
    const float* bconv = (const float*)d_in[3];
    const float* Wfc   = (const float*)d_in[4];
    const float* bfc   = (const float*)d_in[5];
    const int*   esrc  = (const int*)d_in[6];
    const int*   edst  = (const int*)d_in[7];
    float* out = (float*)d_out;

    char* ws = (char*)d_ws;
    size_t off = 0;
    auto alloc = [&](size_t bytes) -> void* {
        void* p = (void*)(ws + off);
        off = (off + bytes + 255) & ~(size_t)255;
        return p;
    };
    int*   rowptr = (int*)  alloc((size_t)(NN + 1) * 4);
    int*   cursor = (int*)  alloc((size_t)NN * 4);
    int*   cnt    = (int*)  alloc((size_t)NN * 4);
    int*   col    = (int*)  alloc((size_t)EE * 4);
    float* wgt    = (float*)alloc((size_t)EE * 4);
    float* logits = (float*)alloc(256 * 4);
    size_t fixed = off;

    int BCH = 0;
    for (int b = 32; b >= 1; b >>= 1) {
        size_t need = fixed + (size_t)KK * NN * (size_t)b * 16 * 4;
        if (need <= ws_size) { BCH = b; break; }
    }
    if (BCH == 0) {  // ws too small even for BCH=1 (~31 MB): make it visible
        sentinel_kernel<<<1, 256, 0, stream>>>(out);
        return;
    }
    float* Xall = (float*)(ws + fixed);

    init_counts<<<(NN + 255) / 256, 256, 0, stream>>>(cnt, logits);
    hist_kernel<<<(EE + 255) / 256, 256, 0, stream>>>(esrc, cnt);
    scan_kernel<<<1, 1024, 0, stream>>>(cnt, rowptr, cursor);
    scatter_kernel<<<(EE + 255) / 256, 256, 0, stream>>>(esrc, edst, ew, cursor, col, wgt);

    switch (BCH) {
        case 32: run_passes<32>(x, W, bconv, Wfc, rowptr, col, wgt, Xall, logits, stream); break;
        case 16: run_passes<16>(x, W, bconv, Wfc, rowptr, col, wgt, Xall, logits, stream); break;
        case 8:  run_passes<8>(x, W, bconv, Wfc, rowptr, col, wgt, Xall, logits, stream); break;
        case 4:  run_passes<4>(x, W, bconv, Wfc, rowptr, col, wgt, Xall, logits, stream); break;
        case 2:  run_passes<2 >(x, W, bconv, Wfc, rowptr, col, wgt, Xall, logits, stream); break;
        default: run_passes<1 >(x, W, bconv, Wfc, rowptr, col, wgt, Xall, logits, stream); break;
    }

    lsm_kernel<<<1, 64, 0, stream>>>(logits, bfc, out);
}

// Round 4
// 3841.356 us; speedup vs baseline: 2.5104x; 1.1888x over previous
//
#include <hip/hip_runtime.h>
#include <math.h>

// Problem dims (fixed)
#define NN 16384
#define BB 32
#define HH 15
#define KK 25
#define GG 64
#define CC 6
#define EE (NN * 32)
#define NG ((size_t)NN * GG)
#define NBLK 2048   // final2 blocks = NN/8

// ---------------- CSR build ----------------

__global__ void init_counts(int* __restrict__ cnt, float* __restrict__ logits) {
    int t = blockIdx.x * 256 + threadIdx.x;
    if (t < NN) cnt[t] = 0;
    if (t < BB * CC) logits[t] = 0.f;
}

__global__ void hist_kernel(const int* __restrict__ src, int* __restrict__ cnt) {
    int e = blockIdx.x * 256 + threadIdx.x;
    if (e < EE) atomicAdd(&cnt[src[e]], 1);
}

__global__ __launch_bounds__(1024) void scan_kernel(const int* __restrict__ cnt,
                                                    int* __restrict__ rowptr,
                                                    int* __restrict__ cursor) {
    __shared__ int sums[1024];
    int t = threadIdx.x;
    int base = t * 16;
    int local[16];
    int s = 0;
#pragma unroll
    for (int i = 0; i < 16; ++i) { local[i] = s; s += cnt[base + i]; }
    sums[t] = s;
    __syncthreads();
    for (int off = 1; off < 1024; off <<= 1) {
        int v = (t >= off) ? sums[t - off] : 0;
        __syncthreads();
        sums[t] += v;
        __syncthreads();
    }
    int prefix = (t == 0) ? 0 : sums[t - 1];
#pragma unroll
    for (int i = 0; i < 16; ++i) {
        int rp = prefix + local[i];
        rowptr[base + i] = rp;
        cursor[base + i] = rp;
    }
    if (t == 1023) rowptr[NN] = sums[1023];
}

__global__ void scatter_kernel(const int* __restrict__ src, const int* __restrict__ dst,
                               const float* __restrict__ w, int* __restrict__ cursor,
                               int* __restrict__ col, float* __restrict__ wgt) {
    int e = blockIdx.x * 256 + threadIdx.x;
    if (e < EE) {
        int pos = atomicAdd(&cursor[src[e]], 1);
        col[pos] = dst[e];
        wgt[pos] = w[e];
    }
}

// ---------------- transpose chunk: X0[n][bb][16] for bb in [0,BCH) ----------------

template<int BCH>
__global__ void transpose_t(const float* __restrict__ x, float* __restrict__ X0, int b0) {
    const int C = BCH * 16;
    int t = blockIdx.x * 256 + threadIdx.x;   // t in [0, NN*C)
    int n = t / C;
    int c = t % C;
    int bb = c >> 4;
    int h = c & 15;
    float v = 0.f;
    if (h < HH) v = x[((size_t)(b0 + bb) * NN + n) * HH + h];
    X0[t] = v;
}

// ---------------- SPMM: Xout = alpha * (L @ Xin) + beta * Xprev ----------------
// One row per C threads. Edge metadata loaded lane-parallel into registers,
// broadcast per-edge via readlane (SALU) -> only the gather touches memory.

template<int C>
__global__ __launch_bounds__((C <= 256) ? 256 : C) void spmm_t(
    const int* __restrict__ rowptr, const int* __restrict__ col, const float* __restrict__ wgt,
    const float* __restrict__ Xin, const float* __restrict__ Xprev, float* __restrict__ Xout,
    float alpha, float beta)
{
    constexpr int TPB = (C <= 256) ? 256 : C;
    constexpr int RPB = TPB / C;
    int sub  = threadIdx.x / C;
    int c    = threadIdx.x % C;
    int lane = threadIdx.x & 63;
    int n = blockIdx.x * RPB + sub;
    int e0 = rowptr[n], e1 = rowptr[n + 1];

    float a0 = 0.f, a1 = 0.f, a2 = 0.f, a3 = 0.f;
    for (int base = e0; base < e1; base += 64) {
        int cnt = e1 - base;
        if (cnt > 64) cnt = 64;
        int cv = 0; float wv = 0.f;
        if (lane < cnt) { cv = col[base + lane]; wv = wgt[base + lane]; }
        int j = 0;
        for (; j + 4 <= cnt; j += 4) {
            int i0 = __builtin_amdgcn_readlane(cv, j);
            int i1 = __builtin_amdgcn_readlane(cv, j + 1);
            int i2 = __builtin_amdgcn_readlane(cv, j + 2);
            int i3 = __builtin_amdgcn_readlane(cv, j + 3);
            float w0 = __int_as_float(__builtin_amdgcn_readlane(__float_as_int(wv), j));
            float w1 = __int_as_float(__builtin_amdgcn_readlane(__float_as_int(wv), j + 1));
            float w2 = __int_as_float(__builtin_amdgcn_readlane(__float_as_int(wv), j + 2));
            float w3 = __int_as_float(__builtin_amdgcn_readlane(__float_as_int(wv), j + 3));
            float x0 = Xin[(size_t)i0 * C + c];
            float x1 = Xin[(size_t)i1 * C + c];
            float x2 = Xin[(size_t)i2 * C + c];
            float x3 = Xin[(size_t)i3 * C + c];
            a0 = fmaf(w0, x0, a0);
            a1 = fmaf(w1, x1, a1);
            a2 = fmaf(w2, x2, a2);
            a3 = fmaf(w3, x3, a3);
        }
        for (; j < cnt; ++j) {
            int i0 = __builtin_amdgcn_readlane(cv, j);
            float w0 = __int_as_float(__builtin_amdgcn_readlane(__float_as_int(wv), j));
            a0 = fmaf(w0, Xin[(size_t)i0 * C + c], a0);
        }
    }
    float acc = (a0 + a1) + (a2 + a3);
    size_t o = (size_t)n * C + c;
    float r = alpha * acc;
    if (beta != 0.f) r = fmaf(beta, Xprev[o], r);
    Xout[o] = r;
}

// ---------------- final2: g-major contraction + bias + relu + FC partials ----------------
// 256 threads = 4 waves; wave = one node-pair set; thread = (node-pair nl, g).
// 8 nodes per block -> NBLK = NN/8 = 2048 blocks.

template<int BCH>
__global__ __launch_bounds__(256) void final2_t(
    const float* __restrict__ Xall, const float* __restrict__ W,
    const float* __restrict__ b_conv, const float* __restrict__ Wfc,
    float* __restrict__ partials, int b0)
{
    constexpr int C = BCH * 16;
    constexpr int NPB = 8;
    __shared__ float sx[NPB * C];
    __shared__ float sred[4][BCH * CC];

    int tid = threadIdx.x;
    int nl  = tid >> 6;   // wave id 0..3
    int g   = tid & 63;
    int nbase = blockIdx.x * NPB;

    float acc[2][BCH];
#pragma unroll
    for (int i = 0; i < 2; ++i)
#pragma unroll
        for (int bb = 0; bb < BCH; ++bb) acc[i][bb] = 0.f;

    for (int k = 0; k < KK; ++k) {
        __syncthreads();
        const float* xsrc = Xall + ((size_t)k * NN + nbase) * C;
        for (int idx = tid; idx < NPB * C; idx += 256) sx[idx] = xsrc[idx];
        __syncthreads();

        const float* Wk = W + k * (HH * GG);
        float wreg[HH];
#pragma unroll
        for (int h = 0; h < HH; ++h) wreg[h] = Wk[h * GG + g];

#pragma unroll
        for (int node = 0; node < 2; ++node) {
            const float4* xq = (const float4*)(sx + (nl * 2 + node) * C);
#pragma unroll
            for (int bb = 0; bb < BCH; ++bb) {
                float4 q0 = xq[bb * 4 + 0];
                float4 q1 = xq[bb * 4 + 1];
                float4 q2 = xq[bb * 4 + 2];
                float4 q3 = xq[bb * 4 + 3];
                float a = acc[node][bb];
                a = fmaf(q0.x, wreg[0], a);
                a = fmaf(q0.y, wreg[1], a);
                a = fmaf(q0.z, wreg[2], a);
                a = fmaf(q0.w, wreg[3], a);
                a = fmaf(q1.x, wreg[4], a);
                a = fmaf(q1.y, wreg[5], a);
                a = fmaf(q1.z, wreg[6], a);
                a = fmaf(q1.w, wreg[7], a);
                a = fmaf(q2.x, wreg[8], a);
                a = fmaf(q2.y, wreg[9], a);
                a = fmaf(q2.z, wreg[10], a);
                a = fmaf(q2.w, wreg[11], a);
                a = fmaf(q3.x, wreg[12], a);
                a = fmaf(q3.y, wreg[13], a);
                a = fmaf(q3.z, wreg[14], a);
                acc[node][bb] = a;      // q3.w is the h=15 pad, skipped
            }
        }
    }

    // bias + relu + FC partials
    float bias = b_conv[g];
    float part[BCH][CC];
#pragma unroll
    for (int bb = 0; bb < BCH; ++bb)
#pragma unroll
        for (int c = 0; c < CC; ++c) part[bb][c] = 0.f;

#pragma unroll
    for (int node = 0; node < 2; ++node) {
        int n = nbase + nl * 2 + node;
        float wv[CC];
#pragma unroll
        for (int c = 0; c < CC; ++c)
            wv[c] = Wfc[(size_t)c * NG + (size_t)n * GG + g];
#pragma unroll
        for (int bb = 0; bb < BCH; ++bb) {
            float hv = fmaxf(acc[node][bb] + bias, 0.f);
#pragma unroll
            for (int c = 0; c < CC; ++c)
                part[bb][c] = fmaf(hv, wv[c], part[bb][c]);
        }
    }

    // butterfly reduce over the 64 g-lanes
#pragma unroll
    for (int off = 1; off < 64; off <<= 1) {
#pragma unroll
        for (int bb = 0; bb < BCH; ++bb)
#pragma unroll
            for (int c = 0; c < CC; ++c)
                part[bb][c] += __shfl_xor(part[bb][c], off);
    }
    if (g == 0) {
#pragma unroll
        for (int bb = 0; bb < BCH; ++bb)
#pragma unroll
            for (int c = 0; c < CC; ++c)
                sred[nl][bb * CC + c] = part[bb][c];
    }
    __syncthreads();
    if (tid < BCH * CC) {
        float s = sred[0][tid] + sred[1][tid] + sred[2][tid] + sred[3][tid];
        int bb = tid / CC;
        int c  = tid % CC;
        partials[(((size_t)(b0 + bb) * CC + c) * NBLK) + blockIdx.x] = s;
    }
}

// ---------------- partials -> logits ----------------

__global__ __launch_bounds__(256) void reduce_logits(const float* __restrict__ partials,
                                                     float* __restrict__ logits) {
    int idx = blockIdx.x;   // b*CC + c
    const float* p = partials + (size_t)idx * NBLK;
    float s = 0.f;
    for (int i = threadIdx.x; i < NBLK; i += 256) s += p[i];
#pragma unroll
    for (int off = 1; off < 64; off <<= 1) s += __shfl_xor(s, off);
    __shared__ float sr[4];
    if ((threadIdx.x & 63) == 0) sr[threadIdx.x >> 6] = s;
    __syncthreads();
    if (threadIdx.x == 0) logits[idx] = sr[0] + sr[1] + sr[2] + sr[3];
}

// ---------------- log_softmax ----------------

__global__ void lsm_kernel(const float* __restrict__ logits, const float* __restrict__ b_fc,
                           float* __restrict__ out) {
    int b = threadIdx.x;
    if (b >= BB) return;
    float v[CC];
    float m = -1e30f;
#pragma unroll
    for (int c = 0; c < CC; ++c) {
        v[c] = logits[b * CC + c] + b_fc[c];
        m = fmaxf(m, v[c]);
    }
    float s = 0.f;
#pragma unroll
    for (int c = 0; c < CC; ++c) s += expf(v[c] - m);
    float ls = m + logf(s);
#pragma unroll
    for (int c = 0; c < CC; ++c) out[b * CC + c] = v[c] - ls;
}

__global__ void sentinel_kernel(float* __restrict__ out) {
    int t = threadIdx.x;
    if (t < BB * CC) out[t] = -12345.f;
}

// ---------------- per-tier pass driver ----------------

template<int BCH>
static void run_passes(const float* x, const float* W, const float* bconv, const float* Wfc,
                       const int* rowptr, const int* col, const float* wgt,
                       float* Xall, float* partials, hipStream_t stream)
{
    constexpr int C = BCH * 16;
    constexpr int TPB = (C <= 256) ? 256 : C;
    constexpr int RPB = TPB / C;
    const size_t slice = (size_t)NN * C;

    for (int p = 0; p < BB / BCH; ++p) {
        int b0 = p * BCH;
        transpose_t<BCH><<<(NN * C) / 256, 256, 0, stream>>>(x, Xall, b0);
        // X1 = L @ X0
        spmm_t<C><<<NN / RPB, TPB, 0, stream>>>(
            rowptr, col, wgt, Xall, Xall, Xall + slice, 1.f, 0.f);
        // Xk = 2 L Xk-1 - Xk-2
        for (int k = 2; k < KK; ++k) {
            spmm_t<C><<<NN / RPB, TPB, 0, stream>>>(
                rowptr, col, wgt,
                Xall + (size_t)(k - 1) * slice,
                Xall + (size_t)(k - 2) * slice,
                Xall + (size_t)k * slice, 2.f, -1.f);
        }
        final2_t<BCH><<<NBLK, 256, 0, stream>>>(Xall, W, bconv, Wfc, partials, b0);
    }
}

// ---------------- launch ----------------

extern "C" void kernel_launch(void* const* d_in, const int* in_sizes, int n_in,
                              void* d_out, int out_size, void* d_ws, size_t ws_size,
                              hipStream_t stream) {
    const float* x     = (const float*)d_in[0];
    const float* ew    = (const float*)d_in[1];
    const float* W     = (const float*)d_in[2];
    const float* bconv = (const float*)d_in[3];
    const float* Wfc   = (const float*)d_in[4];
    const float* bfc   = (const float*)d_in[5];
    const int*   esrc  = (const int*)d_in[6];
    const int*   edst  = (const int*)d_in[7];
    float* out = (float*)d_out;

    char* ws = (char*)d_ws;
    size_t off = 0;
    auto alloc = [&](size_t bytes) -> void* {
        void* p = (void*)(ws + off);
        off = (off + bytes + 255) & ~(size_t)255;
        return p;
    };
    int*   rowptr   = (int*)  alloc((size_t)(NN + 1) * 4);
    int*   cursor   = (int*)  alloc((size_t)NN * 4);
    int*   cnt      = (int*)  alloc((size_t)NN * 4);
    int*   col      = (int*)  alloc((size_t)EE * 4);
    float* wgt      = (float*)alloc((size_t)EE * 4);
    float* logits   = (float*)alloc(256 * 4);
    float* partials = (float*)alloc((size_t)BB * CC * NBLK * 4);
    size_t fixed = off;

    int BCH = 0;
    for (int b = 32; b >= 1; b >>= 1) {
        size_t need = fixed + (size_t)KK * NN * (size_t)b * 16 * 4;
        if (need <= ws_size) { BCH = b; break; }
    }
    if (BCH == 0) {  // ws too small even for BCH=1 (~33 MB): make it visible
        sentinel_kernel<<<1, 256, 0, stream>>>(out);
        return;
    }
    float* Xall = (float*)(ws + fixed);

    init_counts<<<(NN + 255) / 256, 256, 0, stream>>>(cnt, logits);
    hist_kernel<<<(EE + 255) / 256, 256, 0, stream>>>(esrc, cnt);
    scan_kernel<<<1, 1024, 0, stream>>>(cnt, rowptr, cursor);
    scatter_kernel<<<(EE + 255) / 256, 256, 0, stream>>>(esrc, edst, ew, cursor, col, wgt);

    switch (BCH) {
        case 32: run_passes<32>(x, W, bconv, Wfc, rowptr, col, wgt, Xall, partials, stream); break;
        case 16: run_passes<16>(x, W, bconv, Wfc, rowptr, col, wgt, Xall, partials, stream); break;
        case 8:  run_passes<8>(x, W, bconv, Wfc, rowptr, col, wgt, Xall, partials, stream); break;
        case 4:  run_passes<4>(x, W, bconv, Wfc, rowptr, col, wgt, Xall, partials, stream); break;
        case 2:  run_passes<2 >(x, W, bconv, Wfc, rowptr, col, wgt, Xall, partials, stream); break;
        default: run_passes<1 >(x, W, bconv, Wfc, rowptr, col, wgt, Xall, partials, stream); break;
    }

    reduce_logits<<<BB * CC, 256, 0, stream>>>(partials, logits);
    lsm_kernel<<<1, 64, 0, stream>>>(logits, bfc, out);
}

// Round 5
// 2362.968 us; speedup vs baseline: 4.0811x; 1.6256x over previous
//
#include <hip/hip_runtime.h>
#include <hip/hip_bf16.h>
#include <math.h>

// Problem dims (fixed)
#define NN 16384
#define BB 32
#define HH 15
#define KK 25
#define GG 64
#define CC 6
#define EE (NN * 32)
#define NG ((size_t)NN * GG)
#define NBLKF (NN / 4)   // final3 blocks per pass

typedef unsigned int u32;
typedef unsigned short u16;

// ---------------- CSR build ----------------

__global__ void init_counts(int* __restrict__ cnt) {
    int t = blockIdx.x * 256 + threadIdx.x;
    if (t < NN) cnt[t] = 0;
}

__global__ void hist_kernel(const int* __restrict__ src, int* __restrict__ cnt) {
    int e = blockIdx.x * 256 + threadIdx.x;
    if (e < EE) atomicAdd(&cnt[src[e]], 1);
}

__global__ __launch_bounds__(1024) void scan_kernel(const int* __restrict__ cnt,
                                                    int* __restrict__ rowptr,
                                                    int* __restrict__ cursor) {
    __shared__ int sums[1024];
    int t = threadIdx.x;
    int base = t * 16;
    int local[16];
    int s = 0;
#pragma unroll
    for (int i = 0; i < 16; ++i) { local[i] = s; s += cnt[base + i]; }
    sums[t] = s;
    __syncthreads();
    for (int off = 1; off < 1024; off <<= 1) {
        int v = (t >= off) ? sums[t - off] : 0;
        __syncthreads();
        sums[t] += v;
        __syncthreads();
    }
    int prefix = (t == 0) ? 0 : sums[t - 1];
#pragma unroll
    for (int i = 0; i < 16; ++i) {
        int rp = prefix + local[i];
        rowptr[base + i] = rp;
        cursor[base + i] = rp;
    }
    if (t == 1023) rowptr[NN] = sums[1023];
}

__global__ void scatter_kernel(const int* __restrict__ src, const int* __restrict__ dst,
                               const float* __restrict__ w, int* __restrict__ cursor,
                               int* __restrict__ col, float* __restrict__ wgt) {
    int e = blockIdx.x * 256 + threadIdx.x;
    if (e < EE) {
        int pos = atomicAdd(&cursor[src[e]], 1);
        col[pos] = dst[e];
        wgt[pos] = w[e];
    }
}

// ---------------- helpers ----------------

__device__ __forceinline__ u16 f2bf(float f) {
    __hip_bfloat16 b = __float2bfloat16(f);            // RNE
    return *reinterpret_cast<u16*>(&b);
}
__device__ __forceinline__ float bflo(u32 d) { return __uint_as_float(d << 16); }
__device__ __forceinline__ float bfhi(u32 d) { return __uint_as_float(d & 0xffff0000u); }

// ---------------- transpose chunk: packed bf16 rows [n][bb][h-pairs] ----------------
// row = CW dwords; dword j: bb=j>>3, h0=2*(j&7), h1=h0+1 (h=15 -> 0 pad)

template<int BCH>
__global__ void transpose_bf(const float* __restrict__ x, u32* __restrict__ X0, int b0) {
    constexpr int CW = BCH * 8;
    int t = blockIdx.x * 256 + threadIdx.x;     // t = n*CW + j
    int n = t / CW;
    int j = t % CW;
    int bb = j >> 3;
    int h0 = (j & 7) * 2;
    const float* xb = x + ((size_t)(b0 + bb) * NN + n) * HH;
    float lo = xb[h0];
    float hi = (h0 + 1 < HH) ? xb[h0 + 1] : 0.f;
    X0[t] = (u32)f2bf(lo) | ((u32)f2bf(hi) << 16);
}

// ---------------- SPMM on packed bf16 ----------------
// wave per row (4 rows / 256-thr block). BCH==8: lane owns one dword (2 cols).
// BCH<8: lane owns one bf16 col (ushort loads), lanes >= C idle on memory ops.

template<int BCH>
__global__ __launch_bounds__(256) void spmm_bf(
    const int* __restrict__ rowptr, const int* __restrict__ col, const float* __restrict__ wgt,
    const u32* __restrict__ Xin, const u32* __restrict__ Xprev, u32* __restrict__ Xout,
    float alpha, float beta)
{
    constexpr int CW = BCH * 8;       // dwords per row
    constexpr int C  = BCH * 16;      // bf16 cols per row
    int sub  = threadIdx.x >> 6;
    int lane = threadIdx.x & 63;
    int n = blockIdx.x * 4 + sub;
    int e0 = rowptr[n], e1 = rowptr[n + 1];

    if constexpr (BCH == 8) {
        int c = lane;                 // dword index 0..63
        float l0=0.f,h0=0.f,l1=0.f,h1=0.f,l2=0.f,h2=0.f,l3=0.f,h3=0.f;
        for (int base = e0; base < e1; base += 64) {
            int cnt = e1 - base;
            if (cnt > 64) cnt = 64;
            int cv = 0; float wv = 0.f;
            if (lane < cnt) { cv = col[base + lane]; wv = wgt[base + lane]; }
            int j = 0;
            for (; j + 4 <= cnt; j += 4) {
                int i0 = __builtin_amdgcn_readlane(cv, j);
                int i1 = __builtin_amdgcn_readlane(cv, j + 1);
                int i2 = __builtin_amdgcn_readlane(cv, j + 2);
                int i3 = __builtin_amdgcn_readlane(cv, j + 3);
                float w0 = __int_as_float(__builtin_amdgcn_readlane(__float_as_int(wv), j));
                float w1 = __int_as_float(__builtin_amdgcn_readlane(__float_as_int(wv), j + 1));
                float w2 = __int_as_float(__builtin_amdgcn_readlane(__float_as_int(wv), j + 2));
                float w3 = __int_as_float(__builtin_amdgcn_readlane(__float_as_int(wv), j + 3));
                u32 d0 = Xin[(size_t)i0 * CW + c];
                u32 d1 = Xin[(size_t)i1 * CW + c];
                u32 d2 = Xin[(size_t)i2 * CW + c];
                u32 d3 = Xin[(size_t)i3 * CW + c];
                l0 = fmaf(w0, bflo(d0), l0); h0 = fmaf(w0, bfhi(d0), h0);
                l1 = fmaf(w1, bflo(d1), l1); h1 = fmaf(w1, bfhi(d1), h1);
                l2 = fmaf(w2, bflo(d2), l2); h2 = fmaf(w2, bfhi(d2), h2);
                l3 = fmaf(w3, bflo(d3), l3); h3 = fmaf(w3, bfhi(d3), h3);
            }
            for (; j < cnt; ++j) {
                int i0 = __builtin_amdgcn_readlane(cv, j);
                float w0 = __int_as_float(__builtin_amdgcn_readlane(__float_as_int(wv), j));
                u32 d0 = Xin[(size_t)i0 * CW + c];
                l0 = fmaf(w0, bflo(d0), l0); h0 = fmaf(w0, bfhi(d0), h0);
            }
        }
        float rl = alpha * ((l0 + l1) + (l2 + l3));
        float rh = alpha * ((h0 + h1) + (h2 + h3));
        size_t o = (size_t)n * CW + c;
        if (beta != 0.f) {
            u32 dp = Xprev[o];
            rl = fmaf(beta, bflo(dp), rl);
            rh = fmaf(beta, bfhi(dp), rh);
        }
        Xout[o] = (u32)f2bf(rl) | ((u32)f2bf(rh) << 16);
    } else {
        int c = lane;                 // bf16 column 0..C-1 (C<=64)
        const u16* XinU  = (const u16*)Xin;
        const u16* XprevU= (const u16*)Xprev;
        u16* XoutU = (u16*)Xout;
        float a0=0.f,a1=0.f,a2=0.f,a3=0.f;
        bool act = (c < C);
        for (int base = e0; base < e1; base += 64) {
            int cnt = e1 - base;
            if (cnt > 64) cnt = 64;
            int cv = 0; float wv = 0.f;
            if (lane < cnt) { cv = col[base + lane]; wv = wgt[base + lane]; }
            int j = 0;
            for (; j + 4 <= cnt; j += 4) {
                int i0 = __builtin_amdgcn_readlane(cv, j);
                int i1 = __builtin_amdgcn_readlane(cv, j + 1);
                int i2 = __builtin_amdgcn_readlane(cv, j + 2);
                int i3 = __builtin_amdgcn_readlane(cv, j + 3);
                float w0 = __int_as_float(__builtin_amdgcn_readlane(__float_as_int(wv), j));
                float w1 = __int_as_float(__builtin_amdgcn_readlane(__float_as_int(wv), j + 1));
                float w2 = __int_as_float(__builtin_amdgcn_readlane(__float_as_int(wv), j + 2));
                float w3 = __int_as_float(__builtin_amdgcn_readlane(__float_as_int(wv), j + 3));
                if (act) {
                    float x0 = __uint_as_float((u32)XinU[(size_t)i0 * C + c] << 16);
                    float x1 = __uint_as_float((u32)XinU[(size_t)i1 * C + c] << 16);
                    float x2 = __uint_as_float((u32)XinU[(size_t)i2 * C + c] << 16);
                    float x3 = __uint_as_float((u32)XinU[(size_t)i3 * C + c] << 16);
                    a0 = fmaf(w0, x0, a0);
                    a1 = fmaf(w1, x1, a1);
                    a2 = fmaf(w2, x2, a2);
                    a3 = fmaf(w3, x3, a3);
                }
            }
            for (; j < cnt; ++j) {
                int i0 = __builtin_amdgcn_readlane(cv, j);
                float w0 = __int_as_float(__builtin_amdgcn_readlane(__float_as_int(wv), j));
                if (act) a0 = fmaf(w0, __uint_as_float((u32)XinU[(size_t)i0 * C + c] << 16), a0);
            }
        }
        if (act) {
            float r = alpha * ((a0 + a1) + (a2 + a3));
            size_t o = (size_t)n * C + c;
            if (beta != 0.f)
                r = fmaf(beta, __uint_as_float((u32)XprevU[o] << 16), r);
            XoutU[o] = f2bf(r);
        }
    }
}

// ---------------- final3: wave-per-node, lane = g ----------------
// x row is wave-uniform -> scalar loads + SALU unpack; inner loop pure FMA.

template<int BCH>
__global__ __launch_bounds__(256) void final3_t(
    const u32* __restrict__ Xall, const float* __restrict__ W,
    const float* __restrict__ b_conv, const float* __restrict__ Wfc,
    float* __restrict__ partials, int b0)
{
    constexpr int CW = BCH * 8;
    __shared__ float sred[4][BCH * CC];
    int g   = threadIdx.x & 63;
    int nlu = __builtin_amdgcn_readfirstlane((int)threadIdx.x) >> 6;  // wave id (uniform)
    int n   = blockIdx.x * 4 + nlu;

    float acc[BCH];
#pragma unroll
    for (int bb = 0; bb < BCH; ++bb) acc[bb] = 0.f;

    for (int k = 0; k < KK; ++k) {
        const u32* __restrict__ xrow = Xall + ((size_t)k * NN + n) * CW;  // uniform addr
        const float* __restrict__ Wk = W + k * (HH * GG);
        float wreg[HH];
#pragma unroll
        for (int h = 0; h < HH; ++h) wreg[h] = Wk[h * GG + g];
#pragma unroll
        for (int bb = 0; bb < BCH; ++bb) {
            float a = acc[bb];
#pragma unroll
            for (int p = 0; p < 8; ++p) {
                u32 d = xrow[bb * 8 + p];
                a = fmaf(bflo(d), wreg[2 * p], a);
                if (p < 7) a = fmaf(bfhi(d), wreg[2 * p + 1], a);
            }
            acc[bb] = a;
        }
    }

    // bias + relu + FC partials
    float bias = b_conv[g];
    float wv[CC];
#pragma unroll
    for (int c = 0; c < CC; ++c)
        wv[c] = Wfc[(size_t)c * NG + (size_t)n * GG + g];

#pragma unroll
    for (int bb = 0; bb < BCH; ++bb) {
        float hv = fmaxf(acc[bb] + bias, 0.f);
#pragma unroll
        for (int c = 0; c < CC; ++c) {
            float s = hv * wv[c];
#pragma unroll
            for (int off = 1; off < 64; off <<= 1) s += __shfl_xor(s, off);
            if (g == 0) sred[nlu][bb * CC + c] = s;
        }
    }
    __syncthreads();
    if (threadIdx.x < BCH * CC) {
        float s = sred[0][threadIdx.x] + sred[1][threadIdx.x]
                + sred[2][threadIdx.x] + sred[3][threadIdx.x];
        int bb = threadIdx.x / CC;
        int c  = threadIdx.x % CC;
        partials[((size_t)(b0 + bb) * CC + c) * NBLKF + blockIdx.x] = s;
    }
}

// ---------------- partials -> logits ----------------

__global__ __launch_bounds__(256) void reduce_logits(const float* __restrict__ partials,
                                                     float* __restrict__ logits) {
    int idx = blockIdx.x;   // b*CC + c
    const float* p = partials + (size_t)idx * NBLKF;
    float s = 0.f;
    for (int i = threadIdx.x; i < NBLKF; i += 256) s += p[i];
#pragma unroll
    for (int off = 1; off < 64; off <<= 1) s += __shfl_xor(s, off);
    __shared__ float sr[4];
    if ((threadIdx.x & 63) == 0) sr[threadIdx.x >> 6] = s;
    __syncthreads();
    if (threadIdx.x == 0) logits[idx] = sr[0] + sr[1] + sr[2] + sr[3];
}

// ---------------- log_softmax ----------------

__global__ void lsm_kernel(const float* __restrict__ logits, const float* __restrict__ b_fc,
                           float* __restrict__ out) {
    int b = threadIdx.x;
    if (b >= BB) return;
    float v[CC];
    float m = -1e30f;
#pragma unroll
    for (int c = 0; c < CC; ++c) {
        v[c] = logits[b * CC + c] + b_fc[c];
        m = fmaxf(m, v[c]);
    }
    float s = 0.f;
#pragma unroll
    for (int c = 0; c < CC; ++c) s += expf(v[c] - m);
    float ls = m + logf(s);
#pragma unroll
    for (int c = 0; c < CC; ++c) out[b * CC + c] = v[c] - ls;
}

__global__ void sentinel_kernel(float* __restrict__ out) {
    int t = threadIdx.x;
    if (t < BB * CC) out[t] = -12345.f;
}

// ---------------- per-tier pass driver ----------------

template<int BCH>
static void run_passes(const float* x, const float* W, const float* bconv, const float* Wfc,
                       const int* rowptr, const int* col, const float* wgt,
                       u32* Xall, float* partials, hipStream_t stream)
{
    constexpr int CW = BCH * 8;
    const size_t slice = (size_t)NN * CW;   // dwords per slice

    for (int p = 0; p < BB / BCH; ++p) {
        int b0 = p * BCH;
        transpose_bf<BCH><<<(NN * CW) / 256, 256, 0, stream>>>(x, Xall, b0);
        spmm_bf<BCH><<<NN / 4, 256, 0, stream>>>(
            rowptr, col, wgt, Xall, Xall, Xall + slice, 1.f, 0.f);
        for (int k = 2; k < KK; ++k) {
            spmm_bf<BCH><<<NN / 4, 256, 0, stream>>>(
                rowptr, col, wgt,
                Xall + (size_t)(k - 1) * slice,
                Xall + (size_t)(k - 2) * slice,
                Xall + (size_t)k * slice, 2.f, -1.f);
        }
        final3_t<BCH><<<NBLKF, 256, 0, stream>>>(Xall, W, bconv, Wfc, partials, b0);
    }
}

// ---------------- launch ----------------

extern "C" void kernel_launch(void* const* d_in, const int* in_sizes, int n_in,
                              void* d_out, int out_size, void* d_ws, size_t ws_size,
                              hipStream_t stream) {
    const float* x     = (const float*)d_in[0];
    const float* ew    = (const float*)d_in[1];
    const float* W     = (const float*)d_in[2];
    const float* bconv = (const float*)d_in[3];
    const float* Wfc   = (const float*)d_in[4];
    const float* bfc   = (const float*)d_in[5];
    const int*   esrc  = (const int*)d_in[6];
    const int*   edst  = (const int*)d_in[7];
    float* out = (float*)d_out;

    char* ws = (char*)d_ws;
    size_t off = 0;
    auto alloc = [&](size_t bytes) -> void* {
        void* p = (void*)(ws + off);
        off = (off + bytes + 255) & ~(size_t)255;
        return p;
    };
    int*   rowptr   = (int*)  alloc((size_t)(NN + 1) * 4);
    int*   cursor   = (int*)  alloc((size_t)NN * 4);
    int*   cnt      = (int*)  alloc((size_t)NN * 4);
    int*   col      = (int*)  alloc((size_t)EE * 4);
    float* wgt      = (float*)alloc((size_t)EE * 4);
    float* logits   = (float*)alloc(256 * 4);
    float* partials = (float*)alloc((size_t)BB * CC * NBLKF * 4);
    size_t fixed = off;

    int BCH = 0;
    for (int b = 8; b >= 1; b >>= 1) {
        size_t need = fixed + (size_t)KK * NN * (size_t)b * 16 * 2;   // bf16 slices
        if (need <= ws_size) { BCH = b; break; }
    }
    if (BCH == 0) {
        sentinel_kernel<<<1, 256, 0, stream>>>(out);
        return;
    }
    u32* Xall = (u32*)(ws + fixed);

    init_counts<<<(NN + 255) / 256, 256, 0, stream>>>(cnt);
    hist_kernel<<<(EE + 255) / 256, 256, 0, stream>>>(esrc, cnt);
    scan_kernel<<<1, 1024, 0, stream>>>(cnt, rowptr, cursor);
    scatter_kernel<<<(EE + 255) / 256, 256, 0, stream>>>(esrc, edst, ew, cursor, col, wgt);

    switch (BCH) {
        case 8:  run_passes<8>(x, W, bconv, Wfc, rowptr, col, wgt, Xall, partials, stream); break;
        case 4:  run_passes<4>(x, W, bconv, Wfc, rowptr, col, wgt, Xall, partials, stream); break;
        case 2:  run_passes<2>(x, W, bconv, Wfc, rowptr, col, wgt, Xall, partials, stream); break;
        default: run_passes<1>(x, W, bconv, Wfc, rowptr, col, wgt, Xall, partials, stream); break;
    }

    reduce_logits<<<BB * CC, 256, 0, stream>>>(partials, logits);
    lsm_kernel<<<1, 64, 0, stream>>>(logits, bfc, out);
}

// Round 6
// 1870.756 us; speedup vs baseline: 5.1549x; 1.2631x over previous
//
#include <hip/hip_runtime.h>
#include <hip/hip_bf16.h>
#include <math.h>

// Problem dims (fixed)
#define NN 16384
#define BB 32
#define HH 15
#define KK 25
#define GG 64
#define CC 6
#define EE (NN * 32)
#define NG ((size_t)NN * GG)
#define PSTRIDE 4096      // partials stride (max blocks of any final variant)

typedef unsigned int u32;
typedef unsigned short u16;
typedef __attribute__((ext_vector_type(8))) short bf16x8;
typedef __attribute__((ext_vector_type(4))) float f32x4;

// ---------------- CSR build ----------------

__global__ void init_counts(int* __restrict__ cnt) {
    int t = blockIdx.x * 256 + threadIdx.x;
    if (t < NN) cnt[t] = 0;
}

__global__ void hist_kernel(const int* __restrict__ src, int* __restrict__ cnt) {
    int e = blockIdx.x * 256 + threadIdx.x;
    if (e < EE) atomicAdd(&cnt[src[e]], 1);
}

__global__ __launch_bounds__(1024) void scan_kernel(const int* __restrict__ cnt,
                                                    int* __restrict__ rowptr,
                                                    int* __restrict__ cursor) {
    __shared__ int sums[1024];
    int t = threadIdx.x;
    int base = t * 16;
    int local[16];
    int s = 0;
#pragma unroll
    for (int i = 0; i < 16; ++i) { local[i] = s; s += cnt[base + i]; }
    sums[t] = s;
    __syncthreads();
    for (int off = 1; off < 1024; off <<= 1) {
        int v = (t >= off) ? sums[t - off] : 0;
        __syncthreads();
        sums[t] += v;
        __syncthreads();
    }
    int prefix = (t == 0) ? 0 : sums[t - 1];
#pragma unroll
    for (int i = 0; i < 16; ++i) {
        int rp = prefix + local[i];
        rowptr[base + i] = rp;
        cursor[base + i] = rp;
    }
    if (t == 1023) rowptr[NN] = sums[1023];
}

__global__ void scatter_kernel(const int* __restrict__ src, const int* __restrict__ dst,
                               const float* __restrict__ w, int* __restrict__ cursor,
                               int* __restrict__ col, float* __restrict__ wgt) {
    int e = blockIdx.x * 256 + threadIdx.x;
    if (e < EE) {
        int pos = atomicAdd(&cursor[src[e]], 1);
        col[pos] = dst[e];
        wgt[pos] = w[e];
    }
}

// ---------------- helpers ----------------

__device__ __forceinline__ u16 f2bf(float f) {
    __hip_bfloat16 b = __float2bfloat16(f);            // RNE
    return *reinterpret_cast<u16*>(&b);
}
__device__ __forceinline__ float bflo(u32 d) { return __uint_as_float(d << 16); }
__device__ __forceinline__ float bfhi(u32 d) { return __uint_as_float(d & 0xffff0000u); }

// ---------------- W -> bf16, transposed for MFMA B-frags: WbfT[g][416] ----------------
// flat f = k*16 + h  (h=15 pad and f>=400 are zero)

__global__ void prep_wbf(const float* __restrict__ W, u16* __restrict__ WbfT) {
    int t = blockIdx.x * 256 + threadIdx.x;   // t over 64*416
    if (t >= GG * 416) return;
    int g = t / 416;
    int f = t % 416;
    int k = f >> 4;
    int h = f & 15;
    float v = (k < KK && h < HH) ? W[(k * HH + h) * GG + g] : 0.f;
    WbfT[(size_t)g * 416 + f] = f2bf(v);
}

// ---------------- transpose chunk: packed bf16 rows [n][bb][h-pairs] ----------------

template<int BCH>
__global__ void transpose_bf(const float* __restrict__ x, u32* __restrict__ X0, int b0) {
    constexpr int CW = BCH * 8;
    int t = blockIdx.x * 256 + threadIdx.x;     // t = n*CW + j
    int n = t / CW;
    int j = t % CW;
    int bb = j >> 3;
    int h0 = (j & 7) * 2;
    const float* xb = x + ((size_t)(b0 + bb) * NN + n) * HH;
    float lo = xb[h0];
    float hi = (h0 + 1 < HH) ? xb[h0 + 1] : 0.f;
    X0[t] = (u32)f2bf(lo) | ((u32)f2bf(hi) << 16);
}

// ---------------- SPMM on packed bf16 ----------------

template<int BCH>
__global__ __launch_bounds__(256) void spmm_bf(
    const int* __restrict__ rowptr, const int* __restrict__ col, const float* __restrict__ wgt,
    const u32* __restrict__ Xin, const u32* __restrict__ Xprev, u32* __restrict__ Xout,
    float alpha, float beta)
{
    constexpr int CW = BCH * 8;       // dwords per row
    constexpr int C  = BCH * 16;      // bf16 cols per row
    int sub  = threadIdx.x >> 6;
    int lane = threadIdx.x & 63;
    int n = blockIdx.x * 4 + sub;
    int e0 = rowptr[n], e1 = rowptr[n + 1];

    if constexpr (BCH == 8) {
        int c = lane;                 // dword index 0..63
        float l0=0.f,h0=0.f,l1=0.f,h1=0.f,l2=0.f,h2=0.f,l3=0.f,h3=0.f;
        for (int base = e0; base < e1; base += 64) {
            int cnt = e1 - base;
            if (cnt > 64) cnt = 64;
            int cv = 0; float wv = 0.f;
            if (lane < cnt) { cv = col[base + lane]; wv = wgt[base + lane]; }
            int j = 0;
            for (; j + 4 <= cnt; j += 4) {
                int i0 = __builtin_amdgcn_readlane(cv, j);
                int i1 = __builtin_amdgcn_readlane(cv, j + 1);
                int i2 = __builtin_amdgcn_readlane(cv, j + 2);
                int i3 = __builtin_amdgcn_readlane(cv, j + 3);
                float w0 = __int_as_float(__builtin_amdgcn_readlane(__float_as_int(wv), j));
                float w1 = __int_as_float(__builtin_amdgcn_readlane(__float_as_int(wv), j + 1));
                float w2 = __int_as_float(__builtin_amdgcn_readlane(__float_as_int(wv), j + 2));
                float w3 = __int_as_float(__builtin_amdgcn_readlane(__float_as_int(wv), j + 3));
                u32 d0 = Xin[(size_t)i0 * CW + c];
                u32 d1 = Xin[(size_t)i1 * CW + c];
                u32 d2 = Xin[(size_t)i2 * CW + c];
                u32 d3 = Xin[(size_t)i3 * CW + c];
                l0 = fmaf(w0, bflo(d0), l0); h0 = fmaf(w0, bfhi(d0), h0);
                l1 = fmaf(w1, bflo(d1), l1); h1 = fmaf(w1, bfhi(d1), h1);
                l2 = fmaf(w2, bflo(d2), l2); h2 = fmaf(w2, bfhi(d2), h2);
                l3 = fmaf(w3, bflo(d3), l3); h3 = fmaf(w3, bfhi(d3), h3);
            }
            for (; j < cnt; ++j) {
                int i0 = __builtin_amdgcn_readlane(cv, j);
                float w0 = __int_as_float(__builtin_amdgcn_readlane(__float_as_int(wv), j));
                u32 d0 = Xin[(size_t)i0 * CW + c];
                l0 = fmaf(w0, bflo(d0), l0); h0 = fmaf(w0, bfhi(d0), h0);
            }
        }
        float rl = alpha * ((l0 + l1) + (l2 + l3));
        float rh = alpha * ((h0 + h1) + (h2 + h3));
        size_t o = (size_t)n * CW + c;
        if (beta != 0.f) {
            u32 dp = Xprev[o];
            rl = fmaf(beta, bflo(dp), rl);
            rh = fmaf(beta, bfhi(dp), rh);
        }
        Xout[o] = (u32)f2bf(rl) | ((u32)f2bf(rh) << 16);
    } else {
        int c = lane;                 // bf16 column 0..C-1 (C<=64)
        const u16* XinU  = (const u16*)Xin;
        const u16* XprevU= (const u16*)Xprev;
        u16* XoutU = (u16*)Xout;
        float a0=0.f,a1=0.f,a2=0.f,a3=0.f;
        bool act = (c < C);
        for (int base = e0; base < e1; base += 64) {
            int cnt = e1 - base;
            if (cnt > 64) cnt = 64;
            int cv = 0; float wv = 0.f;
            if (lane < cnt) { cv = col[base + lane]; wv = wgt[base + lane]; }
            int j = 0;
            for (; j + 4 <= cnt; j += 4) {
                int i0 = __builtin_amdgcn_readlane(cv, j);
                int i1 = __builtin_amdgcn_readlane(cv, j + 1);
                int i2 = __builtin_amdgcn_readlane(cv, j + 2);
                int i3 = __builtin_amdgcn_readlane(cv, j + 3);
                float w0 = __int_as_float(__builtin_amdgcn_readlane(__float_as_int(wv), j));
                float w1 = __int_as_float(__builtin_amdgcn_readlane(__float_as_int(wv), j + 1));
                float w2 = __int_as_float(__builtin_amdgcn_readlane(__float_as_int(wv), j + 2));
                float w3 = __int_as_float(__builtin_amdgcn_readlane(__float_as_int(wv), j + 3));
                if (act) {
                    float x0 = __uint_as_float((u32)XinU[(size_t)i0 * C + c] << 16);
                    float x1 = __uint_as_float((u32)XinU[(size_t)i1 * C + c] << 16);
                    float x2 = __uint_as_float((u32)XinU[(size_t)i2 * C + c] << 16);
                    float x3 = __uint_as_float((u32)XinU[(size_t)i3 * C + c] << 16);
                    a0 = fmaf(w0, x0, a0);
                    a1 = fmaf(w1, x1, a1);
                    a2 = fmaf(w2, x2, a2);
                    a3 = fmaf(w3, x3, a3);
                }
            }
            for (; j < cnt; ++j) {
                int i0 = __builtin_amdgcn_readlane(cv, j);
                float w0 = __int_as_float(__builtin_amdgcn_readlane(__float_as_int(wv), j));
                if (act) a0 = fmaf(w0, __uint_as_float((u32)XinU[(size_t)i0 * C + c] << 16), a0);
            }
        }
        if (act) {
            float r = alpha * ((a0 + a1) + (a2 + a3));
            size_t o = (size_t)n * C + c;
            if (beta != 0.f)
                r = fmaf(beta, __uint_as_float((u32)XprevU[o] << 16), r);
            XoutU[o] = f2bf(r);
        }
    }
}

// ---------------- final4: MFMA contraction (BCH==8 only) ----------------
// GEMM: OUT[(n,bb), g] = sum_{f=(k,h16)} X[r][f] * W[f][g], K=400 pad 416, 13 steps of 32.
// Wave = one 16-row M-tile; 4 g-tiles of 16. 2048 blocks.

__global__ __launch_bounds__(256) void final4_t(
    const u32* __restrict__ Xall, const u16* __restrict__ WbfT,
    const float* __restrict__ b_conv, const float* __restrict__ Wfc,
    float* __restrict__ partials, int b0)
{
    const int SLICE_DW = NN * 64;
    __shared__ float sred[4][8 * CC];
    int tid  = threadIdx.x;
    int wid  = tid >> 6;
    int lane = tid & 63;
    int q = lane >> 4;      // k-chunk quarter
    int m = lane & 15;
    int r0 = (blockIdx.x * 4 + wid) * 16;   // M-tile base row; r = n*8 + bb
    int r  = r0 + m;

    f32x4 acc0 = {0.f,0.f,0.f,0.f}, acc1 = {0.f,0.f,0.f,0.f};
    f32x4 acc2 = {0.f,0.f,0.f,0.f}, acc3 = {0.f,0.f,0.f,0.f};

    const u32* abase = Xall + (size_t)r * 8 + (size_t)(q & 1) * 4;
    const u16* bbase = WbfT + (size_t)m * 416 + q * 8;

#pragma unroll
    for (int s = 0; s < 13; ++s) {
        int ks = 2 * s + (q >> 1);
        bf16x8 af = {0,0,0,0,0,0,0,0};
        if (s < 12 || q < 2)
            af = *(const bf16x8*)(abase + (size_t)ks * SLICE_DW);
        bf16x8 bf0 = *(const bf16x8*)(bbase + (size_t)0 * 16 * 416 + s * 32);
        bf16x8 bf1 = *(const bf16x8*)(bbase + (size_t)1 * 16 * 416 + s * 32);
        bf16x8 bf2 = *(const bf16x8*)(bbase + (size_t)2 * 16 * 416 + s * 32);
        bf16x8 bf3 = *(const bf16x8*)(bbase + (size_t)3 * 16 * 416 + s * 32);
        acc0 = __builtin_amdgcn_mfma_f32_16x16x32_bf16(af, bf0, acc0, 0, 0, 0);
        acc1 = __builtin_amdgcn_mfma_f32_16x16x32_bf16(af, bf1, acc1, 0, 0, 0);
        acc2 = __builtin_amdgcn_mfma_f32_16x16x32_bf16(af, bf2, acc2, 0, 0, 0);
        acc3 = __builtin_amdgcn_mfma_f32_16x16x32_bf16(af, bf3, acc3, 0, 0, 0);
    }

    // C/D layout: value acc{gt}[i] -> row rr = r0 + q*4 + i, col g = gt*16 + m
    float part[4][CC];
#pragma unroll
    for (int i = 0; i < 4; ++i)
#pragma unroll
        for (int c = 0; c < CC; ++c) part[i][c] = 0.f;

#pragma unroll
    for (int gt = 0; gt < 4; ++gt) {
        f32x4 a = (gt == 0) ? acc0 : (gt == 1) ? acc1 : (gt == 2) ? acc2 : acc3;
        float bias = b_conv[gt * 16 + m];
#pragma unroll
        for (int i = 0; i < 4; ++i) {
            int rr = r0 + q * 4 + i;
            int nrow = rr >> 3;
            float hv = fmaxf(a[i] + bias, 0.f);
#pragma unroll
            for (int c = 0; c < CC; ++c)
                part[i][c] = fmaf(hv,
                    Wfc[(size_t)c * NG + (size_t)nrow * GG + gt * 16 + m], part[i][c]);
        }
    }

    // reduce over m (g dim), then q<->q^2 (node dim); bb = q*4 + i
#pragma unroll
    for (int o = 1; o < 16; o <<= 1)
#pragma unroll
        for (int i = 0; i < 4; ++i)
#pragma unroll
            for (int c = 0; c < CC; ++c)
                part[i][c] += __shfl_xor(part[i][c], o);
#pragma unroll
    for (int i = 0; i < 4; ++i)
#pragma unroll
        for (int c = 0; c < CC; ++c)
            part[i][c] += __shfl_xor(part[i][c], 32);

    if (m == 0 && q < 2) {
#pragma unroll
        for (int i = 0; i < 4; ++i)
#pragma unroll
            for (int c = 0; c < CC; ++c)
                sred[wid][(q * 4 + i) * CC + c] = part[i][c];
    }
    __syncthreads();
    if (tid < 8 * CC) {
        float s4 = sred[0][tid] + sred[1][tid] + sred[2][tid] + sred[3][tid];
        int bb = tid / CC;
        int c  = tid % CC;
        partials[((size_t)(b0 + bb) * CC + c) * PSTRIDE + blockIdx.x] = s4;
    }
}

// ---------------- final3 (fallback for BCH<8) ----------------

template<int BCH>
__global__ __launch_bounds__(256) void final3_t(
    const u32* __restrict__ Xall, const float* __restrict__ W,
    const float* __restrict__ b_conv, const float* __restrict__ Wfc,
    float* __restrict__ partials, int b0)
{
    constexpr int CW = BCH * 8;
    __shared__ float sred[4][BCH * CC];
    int g   = threadIdx.x & 63;
    int nlu = __builtin_amdgcn_readfirstlane((int)threadIdx.x) >> 6;
    int n   = blockIdx.x * 4 + nlu;

    float acc[BCH];
#pragma unroll
    for (int bb = 0; bb < BCH; ++bb) acc[bb] = 0.f;

    for (int k = 0; k < KK; ++k) {
        const u32* __restrict__ xrow = Xall + ((size_t)k * NN + n) * CW;
        const float* __restrict__ Wk = W + k * (HH * GG);
        float wreg[HH];
#pragma unroll
        for (int h = 0; h < HH; ++h) wreg[h] = Wk[h * GG + g];
#pragma unroll
        for (int bb = 0; bb < BCH; ++bb) {
            float a = acc[bb];
#pragma unroll
            for (int p = 0; p < 8; ++p) {
                u32 d = xrow[bb * 8 + p];
                a = fmaf(bflo(d), wreg[2 * p], a);
                if (p < 7) a = fmaf(bfhi(d), wreg[2 * p + 1], a);
            }
            acc[bb] = a;
        }
    }

    float bias = b_conv[g];
    float wv[CC];
#pragma unroll
    for (int c = 0; c < CC; ++c)
        wv[c] = Wfc[(size_t)c * NG + (size_t)n * GG + g];

#pragma unroll
    for (int bb = 0; bb < BCH; ++bb) {
        float hv = fmaxf(acc[bb] + bias, 0.f);
#pragma unroll
        for (int c = 0; c < CC; ++c) {
            float s = hv * wv[c];
#pragma unroll
            for (int off = 1; off < 64; off <<= 1) s += __shfl_xor(s, off);
            if (g == 0) sred[nlu][bb * CC + c] = s;
        }
    }
    __syncthreads();
    if (threadIdx.x < BCH * CC) {
        float s = sred[0][threadIdx.x] + sred[1][threadIdx.x]
                + sred[2][threadIdx.x] + sred[3][threadIdx.x];
        int bb = threadIdx.x / CC;
        int c  = threadIdx.x % CC;
        partials[((size_t)(b0 + bb) * CC + c) * PSTRIDE + blockIdx.x] = s;
    }
}

// ---------------- partials -> logits ----------------

__global__ __launch_bounds__(256) void reduce_logits(const float* __restrict__ partials,
                                                     float* __restrict__ logits, int nblk) {
    int idx = blockIdx.x;   // b*CC + c
    const float* p = partials + (size_t)idx * PSTRIDE;
    float s = 0.f;
    for (int i = threadIdx.x; i < nblk; i += 256) s += p[i];
#pragma unroll
    for (int off = 1; off < 64; off <<= 1) s += __shfl_xor(s, off);
    __shared__ float sr[4];
    if ((threadIdx.x & 63) == 0) sr[threadIdx.x >> 6] = s;
    __syncthreads();
    if (threadIdx.x == 0) logits[idx] = sr[0] + sr[1] + sr[2] + sr[3];
}

// ---------------- log_softmax ----------------

__global__ void lsm_kernel(const float* __restrict__ logits, const float* __restrict__ b_fc,
                           float* __restrict__ out) {
    int b = threadIdx.x;
    if (b >= BB) return;
    float v[CC];
    float m = -1e30f;
#pragma unroll
    for (int c = 0; c < CC; ++c) {
        v[c] = logits[b * CC + c] + b_fc[c];
        m = fmaxf(m, v[c]);
    }
    float s = 0.f;
#pragma unroll
    for (int c = 0; c < CC; ++c) s += expf(v[c] - m);
    float ls = m + logf(s);
#pragma unroll
    for (int c = 0; c < CC; ++c) out[b * CC + c] = v[c] - ls;
}

__global__ void sentinel_kernel(float* __restrict__ out) {
    int t = threadIdx.x;
    if (t < BB * CC) out[t] = -12345.f;
}

// ---------------- per-tier pass driver ----------------

template<int BCH>
static void run_passes(const float* x, const float* W, const u16* WbfT,
                       const float* bconv, const float* Wfc,
                       const int* rowptr, const int* col, const float* wgt,
                       u32* Xall, float* partials, hipStream_t stream)
{
    constexpr int CW = BCH * 8;
    const size_t slice = (size_t)NN * CW;   // dwords per slice

    for (int p = 0; p < BB / BCH; ++p) {
        int b0 = p * BCH;
        transpose_bf<BCH><<<(NN * CW) / 256, 256, 0, stream>>>(x, Xall, b0);
        spmm_bf<BCH><<<NN / 4, 256, 0, stream>>>(
            rowptr, col, wgt, Xall, Xall, Xall + slice, 1.f, 0.f);
        for (int k = 2; k < KK; ++k) {
            spmm_bf<BCH><<<NN / 4, 256, 0, stream>>>(
                rowptr, col, wgt,
                Xall + (size_t)(k - 1) * slice,
                Xall + (size_t)(k - 2) * slice,
                Xall + (size_t)k * slice, 2.f, -1.f);
        }
        if constexpr (BCH == 8) {
            final4_t<<<2048, 256, 0, stream>>>(Xall, WbfT, bconv, Wfc, partials, b0);
        } else {
            final3_t<BCH><<<NN / 4, 256, 0, stream>>>(Xall, W, bconv, Wfc, partials, b0);
        }
    }
}

// ---------------- launch ----------------

extern "C" void kernel_launch(void* const* d_in, const int* in_sizes, int n_in,
                              void* d_out, int out_size, void* d_ws, size_t ws_size,
                              hipStream_t stream) {
    const float* x     = (const float*)d_in[0];
    const float* ew    = (const float*)d_in[1];
    const float* W     = (const float*)d_in[2];
    const float* bconv = (const float*)d_in[3];
    const float* Wfc   = (const float*)d_in[4];
    const float* bfc   = (const float*)d_in[5];
    const int*   esrc  = (const int*)d_in[6];
    const int*   edst  = (const int*)d_in[7];
    float* out = (float*)d_out;

    char* ws = (char*)d_ws;
    size_t off = 0;
    auto alloc = [&](size_t bytes) -> void* {
        void* p = (void*)(ws + off);
        off = (off + bytes + 255) & ~(size_t)255;
        return p;
    };
    int*   rowptr   = (int*)  alloc((size_t)(NN + 1) * 4);
    int*   cursor   = (int*)  alloc((size_t)NN * 4);
    int*   cnt      = (int*)  alloc((size_t)NN * 4);
    int*   col      = (int*)  alloc((size_t)EE * 4);
    float* wgt      = (float*)alloc((size_t)EE * 4);
    float* logits   = (float*)alloc(256 * 4);
    u16*   WbfT     = (u16*)  alloc((size_t)GG * 416 * 2);
    float* partials = (float*)alloc((size_t)BB * CC * PSTRIDE * 4);
    size_t fixed = off;

    int BCH = 0;
    for (int b = 8; b >= 1; b >>= 1) {
        size_t need = fixed + (size_t)KK * NN * (size_t)b * 16 * 2;   // bf16 slices
        if (need <= ws_size) { BCH = b; break; }
    }
    if (BCH == 0) {
        sentinel_kernel<<<1, 256, 0, stream>>>(out);
        return;
    }
    u32* Xall = (u32*)(ws + fixed);

    init_counts<<<(NN + 255) / 256, 256, 0, stream>>>(cnt);
    hist_kernel<<<(EE + 255) / 256, 256, 0, stream>>>(esrc, cnt);
    scan_kernel<<<1, 1024, 0, stream>>>(cnt, rowptr, cursor);
    scatter_kernel<<<(EE + 255) / 256, 256, 0, stream>>>(esrc, edst, ew, cursor, col, wgt);
    prep_wbf<<<(GG * 416 + 255) / 256, 256, 0, stream>>>(W, WbfT);

    switch (BCH) {
        case 8:  run_passes<8>(x, W, WbfT, bconv, Wfc, rowptr, col, wgt, Xall, partials, stream); break;
        case 4:  run_passes<4>(x, W, WbfT, bconv, Wfc, rowptr, col, wgt, Xall, partials, stream); break;
        case 2:  run_passes<2>(x, W, WbfT, bconv, Wfc, rowptr, col, wgt, Xall, partials, stream); break;
        default: run_passes<1>(x, W, WbfT, bconv, Wfc, rowptr, col, wgt, Xall, partials, stream); break;
    }

    int nblk = (BCH == 8) ? 2048 : (NN / 4);
    reduce_logits<<<BB * CC, 256, 0, stream>>>(partials, logits, nblk);
    lsm_kernel<<<1, 64, 0, stream>>>(logits, bfc, out);
}

// Round 7
// 1651.779 us; speedup vs baseline: 5.8383x; 1.1326x over previous
//
#include <hip/hip_runtime.h>
#include <hip/hip_bf16.h>
#include <math.h>

// Problem dims (fixed)
#define NN 16384
#define BB 32
#define HH 15
#define KK 25
#define GG 64
#define CC 6
#define EE (NN * 32)
#define NG ((size_t)NN * GG)
#define PSTRIDE 4096      // partials stride (max blocks of any final variant)

typedef unsigned int u32;
typedef unsigned short u16;
typedef __attribute__((ext_vector_type(8))) short bf16x8;
typedef __attribute__((ext_vector_type(4))) float f32x4;
typedef __attribute__((ext_vector_type(4))) u32 u32x4;

// ---------------- CSR build ----------------

__global__ void init_counts(int* __restrict__ cnt) {
    int t = blockIdx.x * 256 + threadIdx.x;
    if (t < NN) cnt[t] = 0;
}

__global__ void hist_kernel(const int* __restrict__ src, int* __restrict__ cnt) {
    int e = blockIdx.x * 256 + threadIdx.x;
    if (e < EE) atomicAdd(&cnt[src[e]], 1);
}

__global__ __launch_bounds__(1024) void scan_kernel(const int* __restrict__ cnt,
                                                    int* __restrict__ rowptr,
                                                    int* __restrict__ cursor) {
    __shared__ int sums[1024];
    int t = threadIdx.x;
    int base = t * 16;
    int local[16];
    int s = 0;
#pragma unroll
    for (int i = 0; i < 16; ++i) { local[i] = s; s += cnt[base + i]; }
    sums[t] = s;
    __syncthreads();
    for (int off = 1; off < 1024; off <<= 1) {
        int v = (t >= off) ? sums[t - off] : 0;
        __syncthreads();
        sums[t] += v;
        __syncthreads();
    }
    int prefix = (t == 0) ? 0 : sums[t - 1];
#pragma unroll
    for (int i = 0; i < 16; ++i) {
        int rp = prefix + local[i];
        rowptr[base + i] = rp;
        cursor[base + i] = rp;
    }
    if (t == 1023) rowptr[NN] = sums[1023];
}

__global__ void scatter_kernel(const int* __restrict__ src, const int* __restrict__ dst,
                               const float* __restrict__ w, int* __restrict__ cursor,
                               int* __restrict__ col, float* __restrict__ wgt) {
    int e = blockIdx.x * 256 + threadIdx.x;
    if (e < EE) {
        int pos = atomicAdd(&cursor[src[e]], 1);
        col[pos] = dst[e];
        wgt[pos] = w[e];
    }
}

// ---------------- helpers ----------------

__device__ __forceinline__ u16 f2bf(float f) {
    __hip_bfloat16 b = __float2bfloat16(f);            // RNE
    return *reinterpret_cast<u16*>(&b);
}
__device__ __forceinline__ float bflo(u32 d) { return __uint_as_float(d << 16); }
__device__ __forceinline__ float bfhi(u32 d) { return __uint_as_float(d & 0xffff0000u); }

// ---------------- W -> bf16, transposed for MFMA B-frags: WbfT[g][416] ----------------

__global__ void prep_wbf(const float* __restrict__ W, u16* __restrict__ WbfT) {
    int t = blockIdx.x * 256 + threadIdx.x;   // t over 64*416
    if (t >= GG * 416) return;
    int g = t / 416;
    int f = t % 416;
    int k = f >> 4;
    int h = f & 15;
    float v = (k < KK && h < HH) ? W[(k * HH + h) * GG + g] : 0.f;
    WbfT[(size_t)g * 416 + f] = f2bf(v);
}

// ---------------- transpose chunk: packed bf16 rows [n][bb][h-pairs] ----------------

template<int BCH>
__global__ void transpose_bf(const float* __restrict__ x, u32* __restrict__ X0, int b0) {
    constexpr int CW = BCH * 8;
    int t = blockIdx.x * 256 + threadIdx.x;     // t = n*CW + j
    int n = t / CW;
    int j = t % CW;
    int bb = j >> 3;
    int h0 = (j & 7) * 2;
    const float* xb = x + ((size_t)(b0 + bb) * NN + n) * HH;
    float lo = xb[h0];
    float hi = (h0 + 1 < HH) ? xb[h0 + 1] : 0.f;
    X0[t] = (u32)f2bf(lo) | ((u32)f2bf(hi) << 16);
}

// ---------------- SPMM quad-gather (BCH==8): 4 edges per dwordx4 load ----------------
// wave per row; lane = (grp = edge slot 0..3, m16 = dword-quad 0..15).
// One global_load_dwordx4 gathers 4 edges x 16B = 1KB. 2 quads unrolled -> 8 edges in flight.

__global__ __launch_bounds__(256) void spmm_bf8(
    const int* __restrict__ rowptr, const int* __restrict__ col, const float* __restrict__ wgt,
    const u32* __restrict__ Xin, const u32* __restrict__ Xprev, u32* __restrict__ Xout,
    float alpha, float beta)
{
    int sub  = threadIdx.x >> 6;
    int lane = threadIdx.x & 63;
    int n = blockIdx.x * 4 + sub;
    int e0 = rowptr[n], e1 = rowptr[n + 1];
    int grp = lane >> 4;        // edge slot
    int m16 = lane & 15;        // dword-quad within row

    float al[4] = {0.f,0.f,0.f,0.f}, ah[4] = {0.f,0.f,0.f,0.f};
    float bl[4] = {0.f,0.f,0.f,0.f}, bh[4] = {0.f,0.f,0.f,0.f};

    for (int base = e0; base < e1; base += 64) {
        int cnt = e1 - base;
        if (cnt > 64) cnt = 64;
        int cv = 0; float wv = 0.f;
        if (lane < cnt) { cv = col[base + lane]; wv = wgt[base + lane]; }
        int j = 0;
        for (; j + 8 <= cnt; j += 8) {
            int   iA = __shfl(cv, j + grp);
            float wA = __shfl(wv, j + grp);
            int   iB = __shfl(cv, j + 4 + grp);
            float wB = __shfl(wv, j + 4 + grp);
            u32x4 dA = *(const u32x4*)(Xin + (size_t)iA * 64 + m16 * 4);
            u32x4 dB = *(const u32x4*)(Xin + (size_t)iB * 64 + m16 * 4);
#pragma unroll
            for (int i = 0; i < 4; ++i) {
                al[i] = fmaf(wA, bflo(dA[i]), al[i]);
                ah[i] = fmaf(wA, bfhi(dA[i]), ah[i]);
                bl[i] = fmaf(wB, bflo(dB[i]), bl[i]);
                bh[i] = fmaf(wB, bfhi(dB[i]), bh[i]);
            }
        }
        for (; j < cnt; j += 4) {
            int   iA = __shfl(cv, j + grp);
            float wA = __shfl(wv, j + grp);
            u32x4 dA = *(const u32x4*)(Xin + (size_t)iA * 64 + m16 * 4);
#pragma unroll
            for (int i = 0; i < 4; ++i) {
                al[i] = fmaf(wA, bflo(dA[i]), al[i]);
                ah[i] = fmaf(wA, bfhi(dA[i]), ah[i]);
            }
        }
    }

#pragma unroll
    for (int i = 0; i < 4; ++i) { al[i] += bl[i]; ah[i] += bh[i]; }
#pragma unroll
    for (int off = 16; off < 64; off <<= 1)
#pragma unroll
        for (int i = 0; i < 4; ++i) {
            al[i] += __shfl_xor(al[i], off);
            ah[i] += __shfl_xor(ah[i], off);
        }

    if (grp == 0) {
        size_t o = (size_t)n * 64 + (size_t)m16 * 4;
        u32x4 dp = {0,0,0,0};
        if (beta != 0.f) dp = *(const u32x4*)(Xprev + o);
        u32x4 r;
#pragma unroll
        for (int i = 0; i < 4; ++i) {
            float rl = alpha * al[i];
            float rh = alpha * ah[i];
            if (beta != 0.f) {
                rl = fmaf(beta, bflo(dp[i]), rl);
                rh = fmaf(beta, bfhi(dp[i]), rh);
            }
            r[i] = (u32)f2bf(rl) | ((u32)f2bf(rh) << 16);
        }
        *(u32x4*)(Xout + o) = r;
    }
}

// ---------------- SPMM scalar fallback (BCH<8) ----------------

template<int BCH>
__global__ __launch_bounds__(256) void spmm_bf(
    const int* __restrict__ rowptr, const int* __restrict__ col, const float* __restrict__ wgt,
    const u32* __restrict__ Xin, const u32* __restrict__ Xprev, u32* __restrict__ Xout,
    float alpha, float beta)
{
    constexpr int C  = BCH * 16;      // bf16 cols per row
    int sub  = threadIdx.x >> 6;
    int lane = threadIdx.x & 63;
    int n = blockIdx.x * 4 + sub;
    int e0 = rowptr[n], e1 = rowptr[n + 1];

    int c = lane;
    const u16* XinU  = (const u16*)Xin;
    const u16* XprevU= (const u16*)Xprev;
    u16* XoutU = (u16*)Xout;
    float a0=0.f,a1=0.f,a2=0.f,a3=0.f;
    bool act = (c < C);
    for (int base = e0; base < e1; base += 64) {
        int cnt = e1 - base;
        if (cnt > 64) cnt = 64;
        int cv = 0; float wv = 0.f;
        if (lane < cnt) { cv = col[base + lane]; wv = wgt[base + lane]; }
        int j = 0;
        for (; j + 4 <= cnt; j += 4) {
            int i0 = __builtin_amdgcn_readlane(cv, j);
            int i1 = __builtin_amdgcn_readlane(cv, j + 1);
            int i2 = __builtin_amdgcn_readlane(cv, j + 2);
            int i3 = __builtin_amdgcn_readlane(cv, j + 3);
            float w0 = __int_as_float(__builtin_amdgcn_readlane(__float_as_int(wv), j));
            float w1 = __int_as_float(__builtin_amdgcn_readlane(__float_as_int(wv), j + 1));
            float w2 = __int_as_float(__builtin_amdgcn_readlane(__float_as_int(wv), j + 2));
            float w3 = __int_as_float(__builtin_amdgcn_readlane(__float_as_int(wv), j + 3));
            if (act) {
                float x0 = __uint_as_float((u32)XinU[(size_t)i0 * C + c] << 16);
                float x1 = __uint_as_float((u32)XinU[(size_t)i1 * C + c] << 16);
                float x2 = __uint_as_float((u32)XinU[(size_t)i2 * C + c] << 16);
                float x3 = __uint_as_float((u32)XinU[(size_t)i3 * C + c] << 16);
                a0 = fmaf(w0, x0, a0);
                a1 = fmaf(w1, x1, a1);
                a2 = fmaf(w2, x2, a2);
                a3 = fmaf(w3, x3, a3);
            }
        }
        for (; j < cnt; ++j) {
            int i0 = __builtin_amdgcn_readlane(cv, j);
            float w0 = __int_as_float(__builtin_amdgcn_readlane(__float_as_int(wv), j));
            if (act) a0 = fmaf(w0, __uint_as_float((u32)XinU[(size_t)i0 * C + c] << 16), a0);
        }
    }
    if (act) {
        float r = alpha * ((a0 + a1) + (a2 + a3));
        size_t o = (size_t)n * C + c;
        if (beta != 0.f)
            r = fmaf(beta, __uint_as_float((u32)XprevU[o] << 16), r);
        XoutU[o] = f2bf(r);
    }
}

// ---------------- final4: MFMA contraction (BCH==8 only) ----------------

__global__ __launch_bounds__(256) void final4_t(
    const u32* __restrict__ Xall, const u16* __restrict__ WbfT,
    const float* __restrict__ b_conv, const float* __restrict__ Wfc,
    float* __restrict__ partials, int b0)
{
    const int SLICE_DW = NN * 64;
    __shared__ float sred[4][8 * CC];
    int tid  = threadIdx.x;
    int wid  = tid >> 6;
    int lane = tid & 63;
    int q = lane >> 4;      // k-chunk quarter
    int m = lane & 15;
    int r0 = (blockIdx.x * 4 + wid) * 16;   // M-tile base row; r = n*8 + bb
    int r  = r0 + m;

    f32x4 acc0 = {0.f,0.f,0.f,0.f}, acc1 = {0.f,0.f,0.f,0.f};
    f32x4 acc2 = {0.f,0.f,0.f,0.f}, acc3 = {0.f,0.f,0.f,0.f};

    const u32* abase = Xall + (size_t)r * 8 + (size_t)(q & 1) * 4;
    const u16* bbase = WbfT + (size_t)m * 416 + q * 8;

#pragma unroll
    for (int s = 0; s < 13; ++s) {
        int ks = 2 * s + (q >> 1);
        bf16x8 af = {0,0,0,0,0,0,0,0};
        if (s < 12 || q < 2)
            af = *(const bf16x8*)(abase + (size_t)ks * SLICE_DW);
        bf16x8 bf0 = *(const bf16x8*)(bbase + (size_t)0 * 16 * 416 + s * 32);
        bf16x8 bf1 = *(const bf16x8*)(bbase + (size_t)1 * 16 * 416 + s * 32);
        bf16x8 bf2 = *(const bf16x8*)(bbase + (size_t)2 * 16 * 416 + s * 32);
        bf16x8 bf3 = *(const bf16x8*)(bbase + (size_t)3 * 16 * 416 + s * 32);
        acc0 = __builtin_amdgcn_mfma_f32_16x16x32_bf16(af, bf0, acc0, 0, 0, 0);
        acc1 = __builtin_amdgcn_mfma_f32_16x16x32_bf16(af, bf1, acc1, 0, 0, 0);
        acc2 = __builtin_amdgcn_mfma_f32_16x16x32_bf16(af, bf2, acc2, 0, 0, 0);
        acc3 = __builtin_amdgcn_mfma_f32_16x16x32_bf16(af, bf3, acc3, 0, 0, 0);
    }

    // C/D layout: value acc{gt}[i] -> row rr = r0 + q*4 + i, col g = gt*16 + m
    float part[4][CC];
#pragma unroll
    for (int i = 0; i < 4; ++i)
#pragma unroll
        for (int c = 0; c < CC; ++c) part[i][c] = 0.f;

#pragma unroll
    for (int gt = 0; gt < 4; ++gt) {
        f32x4 a = (gt == 0) ? acc0 : (gt == 1) ? acc1 : (gt == 2) ? acc2 : acc3;
        float bias = b_conv[gt * 16 + m];
#pragma unroll
        for (int i = 0; i < 4; ++i) {
            int rr = r0 + q * 4 + i;
            int nrow = rr >> 3;
            float hv = fmaxf(a[i] + bias, 0.f);
#pragma unroll
            for (int c = 0; c < CC; ++c)
                part[i][c] = fmaf(hv,
                    Wfc[(size_t)c * NG + (size_t)nrow * GG + gt * 16 + m], part[i][c]);
        }
    }

#pragma unroll
    for (int o = 1; o < 16; o <<= 1)
#pragma unroll
        for (int i = 0; i < 4; ++i)
#pragma unroll
            for (int c = 0; c < CC; ++c)
                part[i][c] += __shfl_xor(part[i][c], o);
#pragma unroll
    for (int i = 0; i < 4; ++i)
#pragma unroll
        for (int c = 0; c < CC; ++c)
            part[i][c] += __shfl_xor(part[i][c], 32);

    if (m == 0 && q < 2) {
#pragma unroll
        for (int i = 0; i < 4; ++i)
#pragma unroll
            for (int c = 0; c < CC; ++c)
                sred[wid][(q * 4 + i) * CC + c] = part[i][c];
    }
    __syncthreads();
    if (tid < 8 * CC) {
        float s4 = sred[0][tid] + sred[1][tid] + sred[2][tid] + sred[3][tid];
        int bb = tid / CC;
        int c  = tid % CC;
        partials[((size_t)(b0 + bb) * CC + c) * PSTRIDE + blockIdx.x] = s4;
    }
}

// ---------------- final3 (fallback for BCH<8) ----------------

template<int BCH>
__global__ __launch_bounds__(256) void final3_t(
    const u32* __restrict__ Xall, const float* __restrict__ W,
    const float* __restrict__ b_conv, const float* __restrict__ Wfc,
    float* __restrict__ partials, int b0)
{
    constexpr int CW = BCH * 8;
    __shared__ float sred[4][BCH * CC];
    int g   = threadIdx.x & 63;
    int nlu = __builtin_amdgcn_readfirstlane((int)threadIdx.x) >> 6;
    int n   = blockIdx.x * 4 + nlu;

    float acc[BCH];
#pragma unroll
    for (int bb = 0; bb < BCH; ++bb) acc[bb] = 0.f;

    for (int k = 0; k < KK; ++k) {
        const u32* __restrict__ xrow = Xall + ((size_t)k * NN + n) * CW;
        const float* __restrict__ Wk = W + k * (HH * GG);
        float wreg[HH];
#pragma unroll
        for (int h = 0; h < HH; ++h) wreg[h] = Wk[h * GG + g];
#pragma unroll
        for (int bb = 0; bb < BCH; ++bb) {
            float a = acc[bb];
#pragma unroll
            for (int p = 0; p < 8; ++p) {
                u32 d = xrow[bb * 8 + p];
                a = fmaf(bflo(d), wreg[2 * p], a);
                if (p < 7) a = fmaf(bfhi(d), wreg[2 * p + 1], a);
            }
            acc[bb] = a;
        }
    }

    float bias = b_conv[g];
    float wv[CC];
#pragma unroll
    for (int c = 0; c < CC; ++c)
        wv[c] = Wfc[(size_t)c * NG + (size_t)n * GG + g];

#pragma unroll
    for (int bb = 0; bb < BCH; ++bb) {
        float hv = fmaxf(acc[bb] + bias, 0.f);
#pragma unroll
        for (int c = 0; c < CC; ++c) {
            float s = hv * wv[c];
#pragma unroll
            for (int off = 1; off < 64; off <<= 1) s += __shfl_xor(s, off);
            if (g == 0) sred[nlu][bb * CC + c] = s;
        }
    }
    __syncthreads();
    if (threadIdx.x < BCH * CC) {
        float s = sred[0][threadIdx.x] + sred[1][threadIdx.x]
                + sred[2][threadIdx.x] + sred[3][threadIdx.x];
        int bb = threadIdx.x / CC;
        int c  = threadIdx.x % CC;
        partials[((size_t)(b0 + bb) * CC + c) * PSTRIDE + blockIdx.x] = s;
    }
}

// ---------------- partials -> logits ----------------

__global__ __launch_bounds__(256) void reduce_logits(const float* __restrict__ partials,
                                                     float* __restrict__ logits, int nblk) {
    int idx = blockIdx.x;   // b*CC + c
    const float* p = partials + (size_t)idx * PSTRIDE;
    float s = 0.f;
    for (int i = threadIdx.x; i < nblk; i += 256) s += p[i];
#pragma unroll
    for (int off = 1; off < 64; off <<= 1) s += __shfl_xor(s, off);
    __shared__ float sr[4];
    if ((threadIdx.x & 63) == 0) sr[threadIdx.x >> 6] = s;
    __syncthreads();
    if (threadIdx.x == 0) logits[idx] = sr[0] + sr[1] + sr[2] + sr[3];
}

// ---------------- log_softmax ----------------

__global__ void lsm_kernel(const float* __restrict__ logits, const float* __restrict__ b_fc,
                           float* __restrict__ out) {
    int b = threadIdx.x;
    if (b >= BB) return;
    float v[CC];
    float m = -1e30f;
#pragma unroll
    for (int c = 0; c < CC; ++c) {
        v[c] = logits[b * CC + c] + b_fc[c];
        m = fmaxf(m, v[c]);
    }
    float s = 0.f;
#pragma unroll
    for (int c = 0; c < CC; ++c) s += expf(v[c] - m);
    float ls = m + logf(s);
#pragma unroll
    for (int c = 0; c < CC; ++c) out[b * CC + c] = v[c] - ls;
}

__global__ void sentinel_kernel(float* __restrict__ out) {
    int t = threadIdx.x;
    if (t < BB * CC) out[t] = -12345.f;
}

// ---------------- per-tier pass driver ----------------

template<int BCH>
static void run_passes(const float* x, const float* W, const u16* WbfT,
                       const float* bconv, const float* Wfc,
                       const int* rowptr, const int* col, const float* wgt,
                       u32* Xall, float* partials, hipStream_t stream)
{
    constexpr int CW = BCH * 8;
    const size_t slice = (size_t)NN * CW;   // dwords per slice

    for (int p = 0; p < BB / BCH; ++p) {
        int b0 = p * BCH;
        transpose_bf<BCH><<<(NN * CW) / 256, 256, 0, stream>>>(x, Xall, b0);
        if constexpr (BCH == 8) {
            spmm_bf8<<<NN / 4, 256, 0, stream>>>(
                rowptr, col, wgt, Xall, Xall, Xall + slice, 1.f, 0.f);
            for (int k = 2; k < KK; ++k) {
                spmm_bf8<<<NN / 4, 256, 0, stream>>>(
                    rowptr, col, wgt,
                    Xall + (size_t)(k - 1) * slice,
                    Xall + (size_t)(k - 2) * slice,
                    Xall + (size_t)k * slice, 2.f, -1.f);
            }
            final4_t<<<2048, 256, 0, stream>>>(Xall, WbfT, bconv, Wfc, partials, b0);
        } else {
            spmm_bf<BCH><<<NN / 4, 256, 0, stream>>>(
                rowptr, col, wgt, Xall, Xall, Xall + slice, 1.f, 0.f);
            for (int k = 2; k < KK; ++k) {
                spmm_bf<BCH><<<NN / 4, 256, 0, stream>>>(
                    rowptr, col, wgt,
                    Xall + (size_t)(k - 1) * slice,
                    Xall + (size_t)(k - 2) * slice,
                    Xall + (size_t)k * slice, 2.f, -1.f);
            }
            final3_t<BCH><<<NN / 4, 256, 0, stream>>>(Xall, W, bconv, Wfc, partials, b0);
        }
    }
}

// ---------------- launch ----------------

extern "C" void kernel_launch(void* const* d_in, const int* in_sizes, int n_in,
                              void* d_out, int out_size, void* d_ws, size_t ws_size,
                              hipStream_t stream) {
    const float* x     = (const float*)d_in[0];
    const float* ew    = (const float*)d_in[1];
    const float* W     = (const float*)d_in[2];
    const float* bconv = (const float*)d_in[3];
    const float* Wfc   = (const float*)d_in[4];
    const float* bfc   = (const float*)d_in[5];
    const int*   esrc  = (const int*)d_in[6];
    const int*   edst  = (const int*)d_in[7];
    float* out = (float*)d_out;

    char* ws = (char*)d_ws;
    size_t off = 0;
    auto alloc = [&](size_t bytes) -> void* {
        void* p = (void*)(ws + off);
        off = (off + bytes + 255) & ~(size_t)255;
        return p;
    };
    int*   rowptr   = (int*)  alloc((size_t)(NN + 1) * 4);
    int*   cursor   = (int*)  alloc((size_t)NN * 4);
    int*   cnt      = (int*)  alloc((size_t)NN * 4);
    int*   col      = (int*)  alloc((size_t)EE * 4);
    float* wgt      = (float*)alloc((size_t)EE * 4);
    float* logits   = (float*)alloc(256 * 4);
    u16*   WbfT     = (u16*)  alloc((size_t)GG * 416 * 2);
    float* partials = (float*)alloc((size_t)BB * CC * PSTRIDE * 4);
    size_t fixed = off;

    int BCH = 0;
    for (int b = 8; b >= 1; b >>= 1) {
        size_t need = fixed + (size_t)KK * NN * (size_t)b * 16 * 2;   // bf16 slices
        if (need <= ws_size) { BCH = b; break; }
    }
    if (BCH == 0) {
        sentinel_kernel<<<1, 256, 0, stream>>>(out);
        return;
    }
    u32* Xall = (u32*)(ws + fixed);

    init_counts<<<(NN + 255) / 256, 256, 0, stream>>>(cnt);
    hist_kernel<<<(EE + 255) / 256, 256, 0, stream>>>(esrc, cnt);
    scan_kernel<<<1, 1024, 0, stream>>>(cnt, rowptr, cursor);
    scatter_kernel<<<(EE + 255) / 256, 256, 0, stream>>>(esrc, edst, ew, cursor, col, wgt);
    prep_wbf<<<(GG * 416 + 255) / 256, 256, 0, stream>>>(W, WbfT);

    switch (BCH) {
        case 8:  run_passes<8>(x, W, WbfT, bconv, Wfc, rowptr, col, wgt, Xall, partials, stream); break;
        case 4:  run_passes<4>(x, W, WbfT, bconv, Wfc, rowptr, col, wgt, Xall, partials, stream); break;
        case 2:  run_passes<2>(x, W, WbfT, bconv, Wfc, rowptr, col, wgt, Xall, partials, stream); break;
        default: run_passes<1>(x, W, WbfT, bconv, Wfc, rowptr, col, wgt, Xall, partials, stream); break;
    }

    int nblk = (BCH == 8) ? 2048 : (NN / 4);
    reduce_logits<<<BB * CC, 256, 0, stream>>>(partials, logits, nblk);
    lsm_kernel<<<1, 64, 0, stream>>>(logits, bfc, out);
}